// Round 3
// baseline (2283.102 us; speedup 1.0000x reference)
//
#include <hip/hip_runtime.h>
#include <math.h>

// ScatterNet_21706764714521 — round 3: fp32 inputs/outputs (per reference),
// bf16 MFMA internally. Workspace ~178 MB (+33.5 MB of d_out as K scratch).

typedef __bf16 bf16;
typedef __bf16 bf16x8 __attribute__((ext_vector_type(8)));
typedef float f32x4 __attribute__((ext_vector_type(4)));

__device__ __forceinline__ float bf2f(bf16 x) { return (float)x; }
__device__ __forceinline__ bf16 f2bf(float x) { return (bf16)x; }

// node record: (x, y, invalid?1e9:0, 0). adjacency = dist<2 && both valid.
__device__ __forceinline__ bool node_adj(float4 a, float4 c) {
    float dx = a.x - c.x, dy = a.y - c.y;
    return (sqrtf(dx * dx + dy * dy) + a.z + c.z) < 2.0f;
}

// ---------------------------------------------------------------------------
// MFMA GEMM core: C(64x64/block) = A(MxK bf16) @ B, fp32 acc.
// BT=false: B fp32 row-major [K][N] (weights, converted during staging).
// BT=true : B bf16 [N][K] (A@B^T).
// 256 threads = 4 waves; wave w computes rows [w*16,w*16+16) x 64 cols.
// ---------------------------------------------------------------------------
template <bool BT>
__device__ __forceinline__ void gemm_acc(const bf16* __restrict__ A, int lda,
                                         const void* __restrict__ Bv, int ldb,
                                         int K, f32x4 acc[4])
{
    __shared__ bf16 As[64][40];   // 80B row stride = 5*16B, keeps 16B alignment
    __shared__ bf16 Bs[64][40];   // stored as [n][k]
    const int t = threadIdx.x;
    const int m0 = blockIdx.y * 64;
    const int n0 = blockIdx.x * 64;
    const int lane = t & 63;
    const int wv = t >> 6;
    const int lr = lane & 15;
    const int kq = lane >> 4;
    const int arow = t >> 2;          // 0..63, 4 threads/row
    const int acol = (t & 3) * 8;     // 0,8,16,24
    const int bkr = t >> 3;           // 0..31
    const int bnc = (t & 7) * 8;      // 0..56

    for (int k0 = 0; k0 < K; k0 += 32) {
        __syncthreads();
        {
            uint4 va = *(const uint4*)(A + (long)(m0 + arow) * lda + k0 + acol);
            *(uint4*)&As[arow][acol] = va;
        }
        if (BT) {
            const bf16* Bm = (const bf16*)Bv;
            uint4 vb = *(const uint4*)(Bm + (long)(n0 + arow) * ldb + k0 + acol);
            *(uint4*)&Bs[arow][acol] = vb;
        } else {
            const float* Bf = (const float*)Bv;
            const float* bp = Bf + (long)(k0 + bkr) * ldb + n0 + bnc;
            float4 f0 = *(const float4*)bp;
            float4 f1 = *(const float4*)(bp + 4);
            Bs[bnc + 0][bkr] = f2bf(f0.x); Bs[bnc + 1][bkr] = f2bf(f0.y);
            Bs[bnc + 2][bkr] = f2bf(f0.z); Bs[bnc + 3][bkr] = f2bf(f0.w);
            Bs[bnc + 4][bkr] = f2bf(f1.x); Bs[bnc + 5][bkr] = f2bf(f1.y);
            Bs[bnc + 6][bkr] = f2bf(f1.z); Bs[bnc + 7][bkr] = f2bf(f1.w);
        }
        __syncthreads();
        bf16x8 af = *(const bf16x8*)&As[wv * 16 + lr][kq * 8];
        #pragma unroll
        for (int nt = 0; nt < 4; ++nt) {
            bf16x8 bfr = *(const bf16x8*)&Bs[nt * 16 + lr][kq * 8];
            acc[nt] = __builtin_amdgcn_mfma_f32_16x16x32_bf16(af, bfr, acc[nt], 0, 0, 0);
        }
    }
}
// D mapping: row = m0 + wv*16 + kq*4 + i, col = n0 + nt*16 + lr.

__global__ __launch_bounds__(256) void k_gemm_bf16(
    const bf16* __restrict__ A, int lda,
    const float* __restrict__ Bm, int ldb,
    bf16* __restrict__ out, int ldo, int K, int relu)
{
    f32x4 acc[4] = {};
    gemm_acc<false>(A, lda, Bm, ldb, K, acc);
    const int lane = threadIdx.x & 63, wv = threadIdx.x >> 6;
    const int lr = lane & 15, kq = lane >> 4;
    const int m0 = blockIdx.y * 64, n0 = blockIdx.x * 64;
    #pragma unroll
    for (int nt = 0; nt < 4; ++nt) {
        int col = n0 + nt * 16 + lr;
        #pragma unroll
        for (int i = 0; i < 4; ++i) {
            int row = m0 + wv * 16 + kq * 4 + i;
            float v = acc[nt][i];
            if (relu) v = fmaxf(v, 0.f);
            out[(long)row * ldo + col] = f2bf(v);
        }
    }
}

// fused feat MLP: emb = elu(x@W1+b1)@W2 + b2, with scattered epilogue outputs
__global__ __launch_bounds__(256) void k_featgemm(
    const float* __restrict__ tracks, const float* __restrict__ dets,
    const float* __restrict__ W1, const float* __restrict__ b1,
    const float* __restrict__ W2, const float* __restrict__ b2,
    bf16* __restrict__ emb_b, float* __restrict__ emb_r0_f,
    float* __restrict__ feat0_f, bf16* __restrict__ feat0_b,
    bf16* __restrict__ demb_b)
{
    __shared__ float xr[64][4];
    __shared__ float w1s[4][256];
    __shared__ float b1s[256];
    __shared__ bf16 As[64][40];
    __shared__ bf16 Bs[64][40];
    const int t = threadIdx.x;
    const int m0 = blockIdx.y * 64;
    const int n0 = blockIdx.x * 64;
    if (t < 64) {
        int gr = m0 + t;
        const float* sp = (gr < 65536) ? (tracks + (long)gr * 4)
                                       : (dets + (long)(gr - 65536) * 4);
        *(float4*)&xr[t][0] = *(const float4*)sp;
    }
    w1s[0][t] = W1[t];       w1s[1][t] = W1[256 + t];
    w1s[2][t] = W1[512 + t]; w1s[3][t] = W1[768 + t];
    b1s[t] = b1[t];
    const int arow = t >> 2, acol = (t & 3) * 8;
    const int bkr = t >> 3, bnc = (t & 7) * 8;
    const int lane = t & 63, wv = t >> 6;
    const int lr = lane & 15, kq = lane >> 4;
    f32x4 acc[4] = {};
    __syncthreads();
    for (int k0 = 0; k0 < 256; k0 += 32) {
        __syncthreads();
        #pragma unroll
        for (int j = 0; j < 8; ++j) {
            int c = k0 + acol + j;
            float v = xr[arow][0] * w1s[0][c] + xr[arow][1] * w1s[1][c]
                    + xr[arow][2] * w1s[2][c] + xr[arow][3] * w1s[3][c] + b1s[c];
            v = v > 0.f ? v : expm1f(v);
            As[arow][acol + j] = f2bf(v);
        }
        const float* bp = W2 + (long)(k0 + bkr) * 256 + n0 + bnc;
        float4 f0 = *(const float4*)bp;
        float4 f1 = *(const float4*)(bp + 4);
        Bs[bnc + 0][bkr] = f2bf(f0.x); Bs[bnc + 1][bkr] = f2bf(f0.y);
        Bs[bnc + 2][bkr] = f2bf(f0.z); Bs[bnc + 3][bkr] = f2bf(f0.w);
        Bs[bnc + 4][bkr] = f2bf(f1.x); Bs[bnc + 5][bkr] = f2bf(f1.y);
        Bs[bnc + 6][bkr] = f2bf(f1.z); Bs[bnc + 7][bkr] = f2bf(f1.w);
        __syncthreads();
        bf16x8 af = *(const bf16x8*)&As[wv * 16 + lr][kq * 8];
        #pragma unroll
        for (int nt = 0; nt < 4; ++nt) {
            bf16x8 bfr = *(const bf16x8*)&Bs[nt * 16 + lr][kq * 8];
            acc[nt] = __builtin_amdgcn_mfma_f32_16x16x32_bf16(af, bfr, acc[nt], 0, 0, 0);
        }
    }
    #pragma unroll
    for (int nt = 0; nt < 4; ++nt) {
        int col = n0 + nt * 16 + lr;
        float bv = b2[col];
        #pragma unroll
        for (int i = 0; i < 4; ++i) {
            int gr = m0 + wv * 16 + kq * 4 + i;
            float v = acc[nt][i] + bv;
            emb_b[(long)gr * 256 + col] = f2bf(v);
            if (gr < 65536) {
                if ((gr & 7) == 0) emb_r0_f[(long)(gr >> 3) * 256 + col] = v;
            } else {
                int dr = gr - 65536;
                long drow = ((long)(dr >> 9) << 10) + 512 + (dr & 511);
                feat0_f[drow * 256 + col] = v;
                feat0_b[drow * 256 + col] = f2bf(v);
                demb_b[(long)dr * 256 + col] = f2bf(v);
            }
        }
    }
}

// out = res1 + acc (fp32 out)
__global__ __launch_bounds__(256) void k_gemm_addres(
    const bf16* __restrict__ A, int lda,
    const float* __restrict__ Bm, int ldb,
    const float* __restrict__ res1, int ldr1,
    float* __restrict__ outf, int ldo, int K)
{
    f32x4 acc[4] = {};
    gemm_acc<false>(A, lda, Bm, ldb, K, acc);
    const int lane = threadIdx.x & 63, wv = threadIdx.x >> 6;
    const int lr = lane & 15, kq = lane >> 4;
    const int m0 = blockIdx.y * 64, n0 = blockIdx.x * 64;
    #pragma unroll
    for (int nt = 0; nt < 4; ++nt) {
        int col = n0 + nt * 16 + lr;
        #pragma unroll
        for (int i = 0; i < 4; ++i) {
            int row = m0 + wv * 16 + kq * 4 + i;
            outf[(long)row * ldo + col] = res1[(long)row * ldr1 + col] + acc[nt][i];
        }
    }
}

// predicted = tr_emb0 + 0.9*(x2_0 + ff2_out); scattered to feat0[b*1024+m]
__global__ __launch_bounds__(256) void k_gemm_pred(
    const bf16* __restrict__ A, int lda,
    const float* __restrict__ Bm, int ldb,
    const float* __restrict__ res1,   // emb_r0_f, stride 256
    const float* __restrict__ res2,   // x2_0, stride 256
    float* __restrict__ outf, bf16* __restrict__ outb, int K)
{
    f32x4 acc[4] = {};
    gemm_acc<false>(A, lda, Bm, ldb, K, acc);
    const int lane = threadIdx.x & 63, wv = threadIdx.x >> 6;
    const int lr = lane & 15, kq = lane >> 4;
    const int m0 = blockIdx.y * 64, n0 = blockIdx.x * 64;
    #pragma unroll
    for (int nt = 0; nt < 4; ++nt) {
        int col = n0 + nt * 16 + lr;
        #pragma unroll
        for (int i = 0; i < 4; ++i) {
            int row = m0 + wv * 16 + kq * 4 + i;     // b*512 + m
            float v = res1[(long)row * 256 + col]
                    + 0.9f * (res2[(long)row * 256 + col] + acc[nt][i]);
            long drow = (long)row + ((row >> 9) << 9);   // b*1024 + m
            long o = drow * 256 + col;
            outf[o] = v;
            outb[o] = f2bf(v);
        }
    }
}

// scores = sigmoid(acc/16) * adj (fp32 out); optional asso copy / zero diag
__global__ __launch_bounds__(256) void k_gemm_logits(
    const bf16* __restrict__ A, long sAz,
    const bf16* __restrict__ Bm, long sBz, int K,
    float* __restrict__ out, int ldo, long sOz,
    const float4* __restrict__ nodes, int nodeOfs,
    float* __restrict__ asso, int flags)
{
    f32x4 acc[4] = {};
    const int z = blockIdx.z;
    gemm_acc<true>(A + z * sAz, 256, Bm + z * sBz, 256, K, acc);
    const int lane = threadIdx.x & 63, wv = threadIdx.x >> 6;
    const int lr = lane & 15, kq = lane >> 4;
    const int m0 = blockIdx.y * 64, n0 = blockIdx.x * 64;
    const float4* nb = nodes + z * 1024 + nodeOfs;
    float4 nrow[4], ncol[4];
    #pragma unroll
    for (int i = 0; i < 4; ++i) nrow[i] = nb[m0 + wv * 16 + kq * 4 + i];
    #pragma unroll
    for (int nt = 0; nt < 4; ++nt) ncol[nt] = nb[n0 + nt * 16 + lr];
    float* ob = out + z * sOz;
    #pragma unroll
    for (int nt = 0; nt < 4; ++nt) {
        int col = n0 + nt * 16 + lr;
        #pragma unroll
        for (int i = 0; i < 4; ++i) {
            int row = m0 + wv * 16 + kq * 4 + i;
            bool adj = node_adj(nrow[i], ncol[nt]);
            if ((flags & 2) && row == col) adj = false;
            float v = 0.f;
            if (adj) v = 1.f / (1.f + __expf(-acc[nt][i] * 0.0625f));
            ob[(long)row * ldo + col] = v;
            if ((flags & 1) && row < 512 && col >= 512)
                asso[(long)z * 262144 + (long)row * 512 + (col - 512)] = v;
        }
    }
}

// LayerNorm (no affine), row length 256 -> bf16 out
__global__ __launch_bounds__(256) void k_ln_bf16(const bf16* __restrict__ x, bf16* __restrict__ out)
{
    __shared__ float lds[8];
    const long row = blockIdx.x;
    const int t = threadIdx.x;
    float v = bf2f(x[row * 256 + t]);
    float sm = v;
    #pragma unroll
    for (int o = 32; o; o >>= 1) sm += __shfl_down(sm, o, 64);
    if ((t & 63) == 0) lds[t >> 6] = sm;
    __syncthreads();
    float mean = (lds[0] + lds[1] + lds[2] + lds[3]) * (1.f / 256.f);
    float d = v - mean;
    float qv = d * d;
    #pragma unroll
    for (int o = 32; o; o >>= 1) qv += __shfl_down(qv, o, 64);
    if ((t & 63) == 0) lds[4 + (t >> 6)] = qv;
    __syncthreads();
    float var = (lds[4] + lds[5] + lds[6] + lds[7]) * (1.f / 256.f);
    out[row * 256 + t] = f2bf(d * rsqrtf(var + 1e-5f));
}

__global__ __launch_bounds__(256) void k_ln_f32(const float* __restrict__ x, bf16* __restrict__ out)
{
    __shared__ float lds[8];
    const long row = blockIdx.x;
    const int t = threadIdx.x;
    float v = x[row * 256 + t];
    float sm = v;
    #pragma unroll
    for (int o = 32; o; o >>= 1) sm += __shfl_down(sm, o, 64);
    if ((t & 63) == 0) lds[t >> 6] = sm;
    __syncthreads();
    float mean = (lds[0] + lds[1] + lds[2] + lds[3]) * (1.f / 256.f);
    float d = v - mean;
    float qv = d * d;
    #pragma unroll
    for (int o = 32; o; o >>= 1) qv += __shfl_down(qv, o, 64);
    if ((t & 63) == 0) lds[4 + (t >> 6)] = qv;
    __syncthreads();
    float var = (lds[4] + lds[5] + lds[6] + lds[7]) * (1.f / 256.f);
    out[row * 256 + t] = f2bf(d * rsqrtf(var + 1e-5f));
}

// encoder attention, r=0 row only. block = one t, wave = one head.
__global__ __launch_bounds__(256) void k_attn(
    const bf16* __restrict__ q, const bf16* __restrict__ k,
    const bf16* __restrict__ v, bf16* __restrict__ o0)
{
    const long t = blockIdx.x;
    const int h = threadIdx.x >> 6;
    const int lane = threadIdx.x & 63;
    const int s = lane >> 3;
    const int dg = lane & 7;
    const bf16* qp = q + t * 256 + h * 64 + dg * 8;
    const bf16* kp = k + (t * 8 + s) * 256 + h * 64 + dg * 8;
    float p = 0.f;
    #pragma unroll
    for (int e = 0; e < 8; ++e) p += bf2f(qp[e]) * bf2f(kp[e]);
    p += __shfl_xor(p, 1, 64);
    p += __shfl_xor(p, 2, 64);
    p += __shfl_xor(p, 4, 64);
    float sc = p * 0.125f;
    float w[8];
    float mx = -1e30f;
    #pragma unroll
    for (int s2 = 0; s2 < 8; ++s2) { w[s2] = __shfl(sc, s2 * 8, 64); mx = fmaxf(mx, w[s2]); }
    float sum = 0.f;
    #pragma unroll
    for (int s2 = 0; s2 < 8; ++s2) { w[s2] = __expf(w[s2] - mx); sum += w[s2]; }
    float rs = 1.f / sum;
    float acc = 0.f;
    const bf16* vp = v + (t * 8) * 256 + h * 64 + lane;
    #pragma unroll
    for (int s2 = 0; s2 < 8; ++s2) acc += w[s2] * bf2f(vp[(long)s2 * 256]);
    o0[t * 256 + h * 64 + lane] = f2bf(acc * rs);
}

__global__ __launch_bounds__(256) void k_nodes(
    const float* __restrict__ tracks, const float* __restrict__ dets,
    const int* __restrict__ tm, const int* __restrict__ dm,
    float4* __restrict__ nodes)
{
    int idx = blockIdx.x * 256 + threadIdx.x;
    int b = idx >> 10;
    int i = idx & 1023;
    float x, y;
    int valid;
    if (i < 512) {
        long o = (long)(b * 512 + i) * 32;
        x = tracks[o]; y = tracks[o + 1];
        valid = (i < tm[b]) ? 1 : 0;
    } else {
        int n = i - 512;
        long o = (long)(b * 512 + n) * 4;
        x = dets[o]; y = dets[o + 1];
        valid = (n < dm[b]) ? 1 : 0;
    }
    nodes[idx] = make_float4(x, y, valid ? 0.f : 1e9f, 0.f);
}

// GAT src/dst dots
__global__ __launch_bounds__(256) void k_srcdst(
    const bf16* __restrict__ hg, const float* __restrict__ av,
    float* __restrict__ src, float* __restrict__ dst)
{
    const long n = blockIdx.x;
    const int h = threadIdx.x >> 6;
    const int lane = threadIdx.x & 63;
    float hv = bf2f(hg[n * 256 + h * 64 + lane]);
    float p0 = hv * av[h * 64 + lane];
    float p1 = hv * av[256 + h * 64 + lane];
    #pragma unroll
    for (int o = 32; o; o >>= 1) { p0 += __shfl_down(p0, o, 64); p1 += __shfl_down(p1, o, 64); }
    if (lane == 0) { src[n * 4 + h] = p0; dst[n * 4 + h] = p1; }
}

// GAT softmax stats (m,s) per (b,i), 4 heads
__global__ __launch_bounds__(256) void k_gatms(
    const float4* __restrict__ nodes,
    const float4* __restrict__ srcv, const float4* __restrict__ dstv,
    float4* __restrict__ m4, float4* __restrict__ s4,
    int nN, int nodeOfs)
{
    const int bi = blockIdx.x;
    const int b = bi / nN;
    const int i = bi - b * nN;
    const float4* nb = nodes + b * 1024 + nodeOfs;
    const float4 ni = nb[i];
    const float4 si = srcv[bi];
    float mv[4] = {-1e9f, -1e9f, -1e9f, -1e9f};
    float sv[4] = {0.f, 0.f, 0.f, 0.f};
    for (int j = threadIdx.x; j < nN; j += 256) {
        float4 nj = nb[j];
        bool adj = node_adj(ni, nj);
        float4 dj = dstv[(long)b * nN + j];
        float e[4];
        e[0] = si.x + dj.x; e[1] = si.y + dj.y; e[2] = si.z + dj.z; e[3] = si.w + dj.w;
        #pragma unroll
        for (int h = 0; h < 4; ++h) {
            float eh = e[h] >= 0.f ? e[h] : 0.2f * e[h];
            eh = adj ? eh : -1e9f;
            float nm = fmaxf(mv[h], eh);
            sv[h] = sv[h] * __expf(fminf(mv[h] - nm, 0.f)) + __expf(fminf(eh - nm, 0.f));
            mv[h] = nm;
        }
    }
    __shared__ float rm[4][256];
    __shared__ float rs[4][256];
    #pragma unroll
    for (int h = 0; h < 4; ++h) { rm[h][threadIdx.x] = mv[h]; rs[h][threadIdx.x] = sv[h]; }
    __syncthreads();
    for (int off = 128; off >= 1; off >>= 1) {
        if ((int)threadIdx.x < off) {
            #pragma unroll
            for (int h = 0; h < 4; ++h) {
                float ma = rm[h][threadIdx.x], mb2 = rm[h][threadIdx.x + off];
                float sa = rs[h][threadIdx.x], sb2 = rs[h][threadIdx.x + off];
                float nm = fmaxf(ma, mb2);
                rm[h][threadIdx.x] = nm;
                rs[h][threadIdx.x] = sa * __expf(fminf(ma - nm, 0.f)) + sb2 * __expf(fminf(mb2 - nm, 0.f));
            }
        }
        __syncthreads();
    }
    if (threadIdx.x == 0) {
        m4[bi] = make_float4(rm[0][0], rm[1][0], rm[2][0], rm[3][0]);
        s4[bi] = make_float4(rs[0][0], rs[1][0], rs[2][0], rs[3][0]);
    }
}

// GAT aggregation: outb = bf16(0.5*elu(sum_j alpha*h_j) + 0.5*res). 2 rows/block.
__global__ __launch_bounds__(256) void k_gatagg(
    const bf16* __restrict__ hg, const float4* __restrict__ nodes,
    const float4* __restrict__ srcv, const float4* __restrict__ dstv,
    const float4* __restrict__ m4, const float4* __restrict__ s4,
    const float* __restrict__ res, int resBatchStride,
    bf16* __restrict__ outb, int nN, int nodeOfs)
{
    __shared__ float wlds[2][1024][4];
    const int t = threadIdx.x;
    const int i_loc = t >> 7;
    const int perB = nN >> 1;
    const int b = blockIdx.x / perB;
    const int ic = blockIdx.x - b * perB;
    const int i = ic * 2 + i_loc;
    const long bi = (long)b * nN + i;
    const float4* nb = nodes + b * 1024 + nodeOfs;
    const float4 ni = nb[i];
    const float4 si = srcv[bi];
    const float4 mi = m4[bi];
    const float4 sv = s4[bi];
    const float r0 = 1.f / fmaxf(sv.x, 1e-30f), r1 = 1.f / fmaxf(sv.y, 1e-30f);
    const float r2 = 1.f / fmaxf(sv.z, 1e-30f), r3 = 1.f / fmaxf(sv.w, 1e-30f);

    const int tl = t & 127;
    for (int j = tl; j < nN; j += 128) {
        float4 nj = nb[j];
        bool adj = node_adj(ni, nj);
        float4 dj = dstv[(long)b * nN + j];
        float e0 = si.x + dj.x; e0 = e0 >= 0.f ? e0 : 0.2f * e0; e0 = adj ? e0 : -1e9f;
        float e1 = si.y + dj.y; e1 = e1 >= 0.f ? e1 : 0.2f * e1; e1 = adj ? e1 : -1e9f;
        float e2 = si.z + dj.z; e2 = e2 >= 0.f ? e2 : 0.2f * e2; e2 = adj ? e2 : -1e9f;
        float e3 = si.w + dj.w; e3 = e3 >= 0.f ? e3 : 0.2f * e3; e3 = adj ? e3 : -1e9f;
        float4 wv;
        wv.x = __expf(fminf(e0 - mi.x, 0.f)) * r0;
        wv.y = __expf(fminf(e1 - mi.y, 0.f)) * r1;
        wv.z = __expf(fminf(e2 - mi.z, 0.f)) * r2;
        wv.w = __expf(fminf(e3 - mi.w, 0.f)) * r3;
        *(float4*)&wlds[i_loc][j][0] = wv;
    }
    __syncthreads();

    const int h = (t >> 5) & 3;
    const int d2 = t & 31;
    const bf16* hp = hg + ((long)b * nN) * 256 + h * 64 + d2 * 2;
    float a0 = 0.f, a1 = 0.f;
    #pragma unroll 4
    for (int j = 0; j < nN; ++j) {
        float wv = wlds[i_loc][j][h];
        unsigned int raw = *(const unsigned int*)(hp + (long)j * 256);
        a0 += wv * __uint_as_float(raw << 16);
        a1 += wv * __uint_as_float(raw & 0xffff0000u);
    }
    float eA = a0 > 0.f ? a0 : expm1f(a0);
    float eB = a1 > 0.f ? a1 : expm1f(a1);
    long ro = (long)b * resBatchStride + (long)i * 256 + h * 64 + d2 * 2;
    float v0 = 0.5f * eA + 0.5f * res[ro];
    float v1 = 0.5f * eB + 0.5f * res[ro + 1];
    long o = bi * 256 + h * 64 + d2 * 2;
    outb[o] = f2bf(v0);
    outb[o + 1] = f2bf(v1);
}

// ---------------------------------------------------------------------------
extern "C" void kernel_launch(void* const* d_in, const int* in_sizes, int n_in,
                              void* d_out, int out_size, void* d_ws, size_t ws_size,
                              hipStream_t stream)
{
    (void)in_sizes; (void)n_in; (void)out_size; (void)ws_size;
    const float* tracks = (const float*)d_in[0];
    const float* dets   = (const float*)d_in[1];
    const int*  tmarks = (const int*)d_in[2];
    const int*  dmarks = (const int*)d_in[3];
    const float* W1   = (const float*)d_in[4];
    const float* b1   = (const float*)d_in[5];
    const float* W2   = (const float*)d_in[6];
    const float* b2   = (const float*)d_in[7];
    const float* Wqkv = (const float*)d_in[8];
    const float* Wo   = (const float*)d_in[9];
    const float* eff1 = (const float*)d_in[10];
    const float* eff2 = (const float*)d_in[11];
    const float* gatW = (const float*)d_in[12];
    const float* gatA = (const float*)d_in[13];
    const float* dgatW = (const float*)d_in[14];
    const float* dgatA = (const float*)d_in[15];
    const float* clsWq = (const float*)d_in[16];
    const float* clsWk = (const float*)d_in[17];
    float* out = (float*)d_out;

    char* wsb = (char*)d_ws;
    size_t off = 0;
    auto take = [&](size_t bytes) -> char* {
        char* p = wsb + off;
        off += (bytes + 255) & ~(size_t)255;
        return p;
    };
    char* R_emb  = take(37748736);   // emb_b (bf16 73728x256); later x20(+0), h2_b(+8388608)
    char* R_r0   = take(8388608);    // emb_r0_f (fp32 8192x256)
    char* R_hln  = take(33554432);   // hln (bf16 65536x256); later f1_b
    char* R_v    = take(33554432);   // v_b; later xq_b(+0), xk_b(+8388608)
    char* R_gat  = take(25165824);   // hg_b(+0), xga_b(+8388608), xgb_b(+16777216)
    char* R_q    = take(4194304);    // q_b
    char* R_o0   = take(4194304);    // o0_b
    char* R_f0f  = take(16777216);   // feat0_f (fp32 16384x256)
    char* R_f0b  = take(8388608);    // feat0_b (bf16)
    char* R_demb = take(4194304);    // demb_b (bf16 8192x256)
    float4* nodes = (float4*)take(262144);
    float4* src4  = (float4*)take(262144);
    float4* dst4  = (float4*)take(262144);
    float4* m4    = (float4*)take(262144);
    float4* s4    = (float4*)take(262144);

    bf16*  emb_b    = (bf16*)R_emb;
    float* emb_r0_f = (float*)R_r0;
    bf16*  hln      = (bf16*)R_hln;
    bf16*  v_b      = (bf16*)R_v;
    bf16*  k_b      = (bf16*)d_out;         // 33.5MB scratch in d_out (100MB); dead before logits
    bf16*  q_b      = (bf16*)R_q;
    bf16*  o0_b     = (bf16*)R_o0;
    float* x20      = (float*)R_emb;        // after emb_b dead
    bf16*  h2_b     = (bf16*)(R_emb + 8388608);
    bf16*  f1_b     = (bf16*)R_hln;         // after hln dead
    float* feat0_f  = (float*)R_f0f;
    bf16*  feat0_b  = (bf16*)R_f0b;
    bf16*  demb_b   = (bf16*)R_demb;
    bf16*  hg_b     = (bf16*)R_gat;
    bf16*  xga_b    = (bf16*)(R_gat + 8388608);
    bf16*  xgb_b    = (bf16*)(R_gat + 16777216);
    bf16*  xq_b     = (bf16*)R_v;           // after v_b dead
    bf16*  xk_b     = (bf16*)(R_v + 8388608);

    // graph + embeddings (fused feat MLP)
    k_nodes<<<64, 256, 0, stream>>>(tracks, dets, tmarks, dmarks, nodes);
    k_featgemm<<<dim3(4, 1152, 1), 256, 0, stream>>>(tracks, dets, W1, b1, W2, b2,
        emb_b, emb_r0_f, feat0_f, feat0_b, demb_b);

    // encoder (only r=0 row needed downstream of attention)
    k_ln_bf16<<<65536, 256, 0, stream>>>(emb_b, hln);
    k_gemm_bf16<<<dim3(4, 1024, 1), 256, 0, stream>>>(hln, 256, Wqkv + 256, 768, k_b, 256, 256, 0);
    k_gemm_bf16<<<dim3(4, 1024, 1), 256, 0, stream>>>(hln, 256, Wqkv + 512, 768, v_b, 256, 256, 0);
    k_gemm_bf16<<<dim3(4, 128, 1), 256, 0, stream>>>(hln, 2048, Wqkv, 768, q_b, 256, 256, 0);
    k_attn<<<8192, 256, 0, stream>>>(q_b, k_b, v_b, o0_b);
    k_gemm_addres<<<dim3(4, 128, 1), 256, 0, stream>>>(o0_b, 256, Wo, 256, emb_r0_f, 256, x20, 256, 256);
    k_ln_f32<<<8192, 256, 0, stream>>>(x20, h2_b);
    k_gemm_bf16<<<dim3(16, 128, 1), 256, 0, stream>>>(h2_b, 256, eff1, 1024, f1_b, 1024, 256, 1);
    k_gemm_pred<<<dim3(4, 128, 1), 256, 0, stream>>>(f1_b, 1024, eff2, 256, emb_r0_f, x20, feat0_f, feat0_b, 1024);

    // main GAT layer 1
    k_gemm_bf16<<<dim3(4, 256, 1), 256, 0, stream>>>(feat0_b, 256, gatW, 256, hg_b, 256, 256, 0);
    k_srcdst<<<16384, 256, 0, stream>>>(hg_b, gatA, (float*)src4, (float*)dst4);
    k_gatms<<<16384, 256, 0, stream>>>(nodes, src4, dst4, m4, s4, 1024, 0);
    k_gatagg<<<8192, 256, 0, stream>>>(hg_b, nodes, src4, dst4, m4, s4, feat0_f, 262144, xga_b, 1024, 0);
    // main GAT layer 2
    k_gemm_bf16<<<dim3(4, 256, 1), 256, 0, stream>>>(xga_b, 256, gatW + 65536, 256, hg_b, 256, 256, 0);
    k_srcdst<<<16384, 256, 0, stream>>>(hg_b, gatA + 512, (float*)src4, (float*)dst4);
    k_gatms<<<16384, 256, 0, stream>>>(nodes, src4, dst4, m4, s4, 1024, 0);
    k_gatagg<<<8192, 256, 0, stream>>>(hg_b, nodes, src4, dst4, m4, s4, feat0_f, 262144, xgb_b, 1024, 0);
    // main scores + asso
    k_gemm_bf16<<<dim3(4, 256, 1), 256, 0, stream>>>(xgb_b, 256, clsWq, 256, xq_b, 256, 256, 0);
    k_gemm_bf16<<<dim3(4, 256, 1), 256, 0, stream>>>(xgb_b, 256, clsWk, 256, xk_b, 256, 256, 0);
    k_gemm_logits<<<dim3(16, 16, 16), 256, 0, stream>>>(xq_b, 262144L, xk_b, 262144L, 256,
        out, 1024, 1048576L, nodes, 0, out + 20971520L, 1);

    // det branch
    k_gemm_bf16<<<dim3(4, 128, 1), 256, 0, stream>>>(demb_b, 256, dgatW, 256, hg_b, 256, 256, 0);
    k_srcdst<<<8192, 256, 0, stream>>>(hg_b, dgatA, (float*)src4, (float*)dst4);
    k_gatms<<<8192, 256, 0, stream>>>(nodes, src4, dst4, m4, s4, 512, 512);
    k_gatagg<<<4096, 256, 0, stream>>>(hg_b, nodes, src4, dst4, m4, s4, feat0_f + 131072, 262144, xga_b, 512, 512);
    k_gemm_bf16<<<dim3(4, 128, 1), 256, 0, stream>>>(xga_b, 256, dgatW + 65536, 256, hg_b, 256, 256, 0);
    k_srcdst<<<8192, 256, 0, stream>>>(hg_b, dgatA + 512, (float*)src4, (float*)dst4);
    k_gatms<<<8192, 256, 0, stream>>>(nodes, src4, dst4, m4, s4, 512, 512);
    k_gatagg<<<4096, 256, 0, stream>>>(hg_b, nodes, src4, dst4, m4, s4, feat0_f + 131072, 262144, xgb_b, 512, 512);
    k_gemm_bf16<<<dim3(4, 128, 1), 256, 0, stream>>>(xgb_b, 256, clsWq + 65536, 256, xq_b, 256, 256, 0);
    k_gemm_bf16<<<dim3(4, 128, 1), 256, 0, stream>>>(xgb_b, 256, clsWk + 65536, 256, xk_b, 256, 256, 0);
    k_gemm_logits<<<dim3(8, 8, 16), 256, 0, stream>>>(xq_b, 131072L, xk_b, 131072L, 256,
        out + 16777216L, 512, 262144L, nodes, 512, (float*)nullptr, 2);
}

// Round 4
// 951.295 us; speedup vs baseline: 2.4000x; 2.4000x over previous
//
#include <hip/hip_runtime.h>
#include <math.h>

// ScatterNet_21706764714521 — round 4: GAT aggregation as MFMA GEMM.
// fp32 I/O, bf16 MFMA internally. Workspace ~181 MB (+33.5 MB d_out scratch).

typedef __bf16 bf16;
typedef __bf16 bf16x8 __attribute__((ext_vector_type(8)));
typedef float f32x4 __attribute__((ext_vector_type(4)));

__device__ __forceinline__ float bf2f(bf16 x) { return (float)x; }
__device__ __forceinline__ bf16 f2bf(float x) { return (bf16)x; }

// node record: (x, y, invalid?1e9:0, 0). adjacency = dist<2 && both valid.
__device__ __forceinline__ bool node_adj(float4 a, float4 c) {
    float dx = a.x - c.x, dy = a.y - c.y;
    return (sqrtf(dx * dx + dy * dy) + a.z + c.z) < 2.0f;
}

// ---------------------------------------------------------------------------
// MFMA GEMM core: C(64x64/block) = A(MxK bf16) @ B, fp32 acc.
// BT=false: B fp32 row-major [K][N] (weights, converted during staging).
// BT=true : B bf16 [N][K] (A@B^T).
// ---------------------------------------------------------------------------
template <bool BT>
__device__ __forceinline__ void gemm_acc(const bf16* __restrict__ A, int lda,
                                         const void* __restrict__ Bv, int ldb,
                                         int K, f32x4 acc[4])
{
    __shared__ bf16 As[64][40];
    __shared__ bf16 Bs[64][40];   // [n][k]
    const int t = threadIdx.x;
    const int m0 = blockIdx.y * 64;
    const int n0 = blockIdx.x * 64;
    const int lane = t & 63;
    const int wv = t >> 6;
    const int lr = lane & 15;
    const int kq = lane >> 4;
    const int arow = t >> 2;
    const int acol = (t & 3) * 8;
    const int bkr = t >> 3;
    const int bnc = (t & 7) * 8;

    for (int k0 = 0; k0 < K; k0 += 32) {
        __syncthreads();
        {
            uint4 va = *(const uint4*)(A + (long)(m0 + arow) * lda + k0 + acol);
            *(uint4*)&As[arow][acol] = va;
        }
        if (BT) {
            const bf16* Bm = (const bf16*)Bv;
            uint4 vb = *(const uint4*)(Bm + (long)(n0 + arow) * ldb + k0 + acol);
            *(uint4*)&Bs[arow][acol] = vb;
        } else {
            const float* Bf = (const float*)Bv;
            const float* bp = Bf + (long)(k0 + bkr) * ldb + n0 + bnc;
            float4 f0 = *(const float4*)bp;
            float4 f1 = *(const float4*)(bp + 4);
            Bs[bnc + 0][bkr] = f2bf(f0.x); Bs[bnc + 1][bkr] = f2bf(f0.y);
            Bs[bnc + 2][bkr] = f2bf(f0.z); Bs[bnc + 3][bkr] = f2bf(f0.w);
            Bs[bnc + 4][bkr] = f2bf(f1.x); Bs[bnc + 5][bkr] = f2bf(f1.y);
            Bs[bnc + 6][bkr] = f2bf(f1.z); Bs[bnc + 7][bkr] = f2bf(f1.w);
        }
        __syncthreads();
        bf16x8 af = *(const bf16x8*)&As[wv * 16 + lr][kq * 8];
        #pragma unroll
        for (int nt = 0; nt < 4; ++nt) {
            bf16x8 bfr = *(const bf16x8*)&Bs[nt * 16 + lr][kq * 8];
            acc[nt] = __builtin_amdgcn_mfma_f32_16x16x32_bf16(af, bfr, acc[nt], 0, 0, 0);
        }
    }
}
// D mapping: row = m0 + wv*16 + kq*4 + i, col = n0 + nt*16 + lr.

__global__ __launch_bounds__(256) void k_gemm_bf16(
    const bf16* __restrict__ A, int lda,
    const float* __restrict__ Bm, int ldb,
    bf16* __restrict__ out, int ldo, int K, int relu)
{
    f32x4 acc[4] = {};
    gemm_acc<false>(A, lda, Bm, ldb, K, acc);
    const int lane = threadIdx.x & 63, wv = threadIdx.x >> 6;
    const int lr = lane & 15, kq = lane >> 4;
    const int m0 = blockIdx.y * 64, n0 = blockIdx.x * 64;
    #pragma unroll
    for (int nt = 0; nt < 4; ++nt) {
        int col = n0 + nt * 16 + lr;
        #pragma unroll
        for (int i = 0; i < 4; ++i) {
            int row = m0 + wv * 16 + kq * 4 + i;
            float v = acc[nt][i];
            if (relu) v = fmaxf(v, 0.f);
            out[(long)row * ldo + col] = f2bf(v);
        }
    }
}

// GAT projection, transposed output: hgT[b][d][j] = (X @ W)[b*nN+j][d]
// A = W^T (staged with fp32->bf16 transpose), B = X (row-major bf16).
__global__ __launch_bounds__(256) void k_gemm_T(
    const bf16* __restrict__ X, const float* __restrict__ W,
    bf16* __restrict__ hgT, int nN, int nLog)
{
    __shared__ bf16 As[64][40];   // [d][k]
    __shared__ bf16 Bs[64][40];   // [node][k]
    const int t = threadIdx.x;
    const int d0 = blockIdx.y * 64;
    const int n0 = blockIdx.x * 64;
    const int arow = t >> 2, acol = (t & 3) * 8;
    const int bkr = t >> 3, bnc = (t & 7) * 8;
    const int lane = t & 63, wv = t >> 6, lr = lane & 15, kq = lane >> 4;
    f32x4 acc[4] = {};
    for (int k0 = 0; k0 < 256; k0 += 32) {
        __syncthreads();
        {
            uint4 vx = *(const uint4*)(X + (long)(n0 + arow) * 256 + k0 + acol);
            *(uint4*)&Bs[arow][acol] = vx;
        }
        {
            const float* wp = W + (long)(k0 + bkr) * 256 + d0 + bnc;
            float4 f0 = *(const float4*)wp;
            float4 f1 = *(const float4*)(wp + 4);
            As[bnc + 0][bkr] = f2bf(f0.x); As[bnc + 1][bkr] = f2bf(f0.y);
            As[bnc + 2][bkr] = f2bf(f0.z); As[bnc + 3][bkr] = f2bf(f0.w);
            As[bnc + 4][bkr] = f2bf(f1.x); As[bnc + 5][bkr] = f2bf(f1.y);
            As[bnc + 6][bkr] = f2bf(f1.z); As[bnc + 7][bkr] = f2bf(f1.w);
        }
        __syncthreads();
        bf16x8 af = *(const bf16x8*)&As[wv * 16 + lr][kq * 8];
        #pragma unroll
        for (int nt = 0; nt < 4; ++nt) {
            bf16x8 bfr = *(const bf16x8*)&Bs[nt * 16 + lr][kq * 8];
            acc[nt] = __builtin_amdgcn_mfma_f32_16x16x32_bf16(af, bfr, acc[nt], 0, 0, 0);
        }
    }
    #pragma unroll
    for (int nt = 0; nt < 4; ++nt) {
        int node = n0 + nt * 16 + lr;
        int b = node >> nLog;
        int j = node & (nN - 1);
        #pragma unroll
        for (int i = 0; i < 4; ++i) {
            int d = d0 + wv * 16 + kq * 4 + i;
            hgT[((long)(b * 256 + d) << nLog) + j] = f2bf(acc[nt][i]);
        }
    }
}

// adjacency bitmask rows via ballot: adjm[b*nN+i][c] bit l = adj(i, c*64+l)
__global__ __launch_bounds__(256) void k_adjmask(
    const float4* __restrict__ nodes, unsigned long long* __restrict__ adjm,
    int nN, int nLog, int nodeOfs)
{
    const int bi = blockIdx.x;
    const int b = bi >> nLog;
    const int i = bi & (nN - 1);
    const float4* nb = nodes + b * 1024 + nodeOfs;
    const float4 ni = nb[i];
    const int t = threadIdx.x;
    const int w = t >> 6, lane = t & 63;
    const int nC = nN >> 6;
    for (int it = 0; it * 256 < nN; ++it) {
        int j = it * 256 + t;
        bool adj = node_adj(ni, nb[j]);
        unsigned long long mask = __ballot(adj);
        if (lane == 0) adjm[(long)bi * nC + it * 4 + w] = mask;
    }
}

// fused feat MLP: emb = elu(x@W1+b1)@W2 + b2, with scattered epilogue outputs
__global__ __launch_bounds__(256) void k_featgemm(
    const float* __restrict__ tracks, const float* __restrict__ dets,
    const float* __restrict__ W1, const float* __restrict__ b1,
    const float* __restrict__ W2, const float* __restrict__ b2,
    bf16* __restrict__ emb_b, float* __restrict__ emb_r0_f,
    float* __restrict__ feat0_f, bf16* __restrict__ feat0_b,
    bf16* __restrict__ demb_b)
{
    __shared__ float xr[64][4];
    __shared__ float w1s[4][256];
    __shared__ float b1s[256];
    __shared__ bf16 As[64][40];
    __shared__ bf16 Bs[64][40];
    const int t = threadIdx.x;
    const int m0 = blockIdx.y * 64;
    const int n0 = blockIdx.x * 64;
    if (t < 64) {
        int gr = m0 + t;
        const float* sp = (gr < 65536) ? (tracks + (long)gr * 4)
                                       : (dets + (long)(gr - 65536) * 4);
        *(float4*)&xr[t][0] = *(const float4*)sp;
    }
    w1s[0][t] = W1[t];       w1s[1][t] = W1[256 + t];
    w1s[2][t] = W1[512 + t]; w1s[3][t] = W1[768 + t];
    b1s[t] = b1[t];
    const int arow = t >> 2, acol = (t & 3) * 8;
    const int bkr = t >> 3, bnc = (t & 7) * 8;
    const int lane = t & 63, wv = t >> 6;
    const int lr = lane & 15, kq = lane >> 4;
    f32x4 acc[4] = {};
    __syncthreads();
    for (int k0 = 0; k0 < 256; k0 += 32) {
        __syncthreads();
        #pragma unroll
        for (int j = 0; j < 8; ++j) {
            int c = k0 + acol + j;
            float v = xr[arow][0] * w1s[0][c] + xr[arow][1] * w1s[1][c]
                    + xr[arow][2] * w1s[2][c] + xr[arow][3] * w1s[3][c] + b1s[c];
            v = v > 0.f ? v : expm1f(v);
            As[arow][acol + j] = f2bf(v);
        }
        const float* bp = W2 + (long)(k0 + bkr) * 256 + n0 + bnc;
        float4 f0 = *(const float4*)bp;
        float4 f1 = *(const float4*)(bp + 4);
        Bs[bnc + 0][bkr] = f2bf(f0.x); Bs[bnc + 1][bkr] = f2bf(f0.y);
        Bs[bnc + 2][bkr] = f2bf(f0.z); Bs[bnc + 3][bkr] = f2bf(f0.w);
        Bs[bnc + 4][bkr] = f2bf(f1.x); Bs[bnc + 5][bkr] = f2bf(f1.y);
        Bs[bnc + 6][bkr] = f2bf(f1.z); Bs[bnc + 7][bkr] = f2bf(f1.w);
        __syncthreads();
        bf16x8 af = *(const bf16x8*)&As[wv * 16 + lr][kq * 8];
        #pragma unroll
        for (int nt = 0; nt < 4; ++nt) {
            bf16x8 bfr = *(const bf16x8*)&Bs[nt * 16 + lr][kq * 8];
            acc[nt] = __builtin_amdgcn_mfma_f32_16x16x32_bf16(af, bfr, acc[nt], 0, 0, 0);
        }
    }
    #pragma unroll
    for (int nt = 0; nt < 4; ++nt) {
        int col = n0 + nt * 16 + lr;
        float bv = b2[col];
        #pragma unroll
        for (int i = 0; i < 4; ++i) {
            int gr = m0 + wv * 16 + kq * 4 + i;
            float v = acc[nt][i] + bv;
            emb_b[(long)gr * 256 + col] = f2bf(v);
            if (gr < 65536) {
                if ((gr & 7) == 0) emb_r0_f[(long)(gr >> 3) * 256 + col] = v;
            } else {
                int dr = gr - 65536;
                long drow = ((long)(dr >> 9) << 10) + 512 + (dr & 511);
                feat0_f[drow * 256 + col] = v;
                feat0_b[drow * 256 + col] = f2bf(v);
                demb_b[(long)dr * 256 + col] = f2bf(v);
            }
        }
    }
}

// out = res1 + acc (fp32 out)
__global__ __launch_bounds__(256) void k_gemm_addres(
    const bf16* __restrict__ A, int lda,
    const float* __restrict__ Bm, int ldb,
    const float* __restrict__ res1, int ldr1,
    float* __restrict__ outf, int ldo, int K)
{
    f32x4 acc[4] = {};
    gemm_acc<false>(A, lda, Bm, ldb, K, acc);
    const int lane = threadIdx.x & 63, wv = threadIdx.x >> 6;
    const int lr = lane & 15, kq = lane >> 4;
    const int m0 = blockIdx.y * 64, n0 = blockIdx.x * 64;
    #pragma unroll
    for (int nt = 0; nt < 4; ++nt) {
        int col = n0 + nt * 16 + lr;
        #pragma unroll
        for (int i = 0; i < 4; ++i) {
            int row = m0 + wv * 16 + kq * 4 + i;
            outf[(long)row * ldo + col] = res1[(long)row * ldr1 + col] + acc[nt][i];
        }
    }
}

// predicted = tr_emb0 + 0.9*(x2_0 + ff2_out); scattered to feat0[b*1024+m]
__global__ __launch_bounds__(256) void k_gemm_pred(
    const bf16* __restrict__ A, int lda,
    const float* __restrict__ Bm, int ldb,
    const float* __restrict__ res1, const float* __restrict__ res2,
    float* __restrict__ outf, bf16* __restrict__ outb, int K)
{
    f32x4 acc[4] = {};
    gemm_acc<false>(A, lda, Bm, ldb, K, acc);
    const int lane = threadIdx.x & 63, wv = threadIdx.x >> 6;
    const int lr = lane & 15, kq = lane >> 4;
    const int m0 = blockIdx.y * 64, n0 = blockIdx.x * 64;
    #pragma unroll
    for (int nt = 0; nt < 4; ++nt) {
        int col = n0 + nt * 16 + lr;
        #pragma unroll
        for (int i = 0; i < 4; ++i) {
            int row = m0 + wv * 16 + kq * 4 + i;     // b*512 + m
            float v = res1[(long)row * 256 + col]
                    + 0.9f * (res2[(long)row * 256 + col] + acc[nt][i]);
            long drow = (long)row + ((row >> 9) << 9);   // b*1024 + m
            long o = drow * 256 + col;
            outf[o] = v;
            outb[o] = f2bf(v);
        }
    }
}

// scores = sigmoid(acc/16) * adj (fp32 out); optional asso copy / zero diag
__global__ __launch_bounds__(256) void k_gemm_logits(
    const bf16* __restrict__ A, long sAz,
    const bf16* __restrict__ Bm, long sBz, int K,
    float* __restrict__ out, int ldo, long sOz,
    const float4* __restrict__ nodes, int nodeOfs,
    float* __restrict__ asso, int flags)
{
    f32x4 acc[4] = {};
    const int z = blockIdx.z;
    gemm_acc<true>(A + z * sAz, 256, Bm + z * sBz, 256, K, acc);
    const int lane = threadIdx.x & 63, wv = threadIdx.x >> 6;
    const int lr = lane & 15, kq = lane >> 4;
    const int m0 = blockIdx.y * 64, n0 = blockIdx.x * 64;
    const float4* nb = nodes + z * 1024 + nodeOfs;
    float4 nrow[4], ncol[4];
    #pragma unroll
    for (int i = 0; i < 4; ++i) nrow[i] = nb[m0 + wv * 16 + kq * 4 + i];
    #pragma unroll
    for (int nt = 0; nt < 4; ++nt) ncol[nt] = nb[n0 + nt * 16 + lr];
    float* ob = out + z * sOz;
    #pragma unroll
    for (int nt = 0; nt < 4; ++nt) {
        int col = n0 + nt * 16 + lr;
        #pragma unroll
        for (int i = 0; i < 4; ++i) {
            int row = m0 + wv * 16 + kq * 4 + i;
            bool adj = node_adj(nrow[i], ncol[nt]);
            if ((flags & 2) && row == col) adj = false;
            float v = 0.f;
            if (adj) v = 1.f / (1.f + __expf(-acc[nt][i] * 0.0625f));
            ob[(long)row * ldo + col] = v;
            if ((flags & 1) && row < 512 && col >= 512)
                asso[(long)z * 262144 + (long)row * 512 + (col - 512)] = v;
        }
    }
}

// LayerNorm (no affine), row length 256 -> bf16 out
__global__ __launch_bounds__(256) void k_ln_bf16(const bf16* __restrict__ x, bf16* __restrict__ out)
{
    __shared__ float lds[8];
    const long row = blockIdx.x;
    const int t = threadIdx.x;
    float v = bf2f(x[row * 256 + t]);
    float sm = v;
    #pragma unroll
    for (int o = 32; o; o >>= 1) sm += __shfl_down(sm, o, 64);
    if ((t & 63) == 0) lds[t >> 6] = sm;
    __syncthreads();
    float mean = (lds[0] + lds[1] + lds[2] + lds[3]) * (1.f / 256.f);
    float d = v - mean;
    float qv = d * d;
    #pragma unroll
    for (int o = 32; o; o >>= 1) qv += __shfl_down(qv, o, 64);
    if ((t & 63) == 0) lds[4 + (t >> 6)] = qv;
    __syncthreads();
    float var = (lds[4] + lds[5] + lds[6] + lds[7]) * (1.f / 256.f);
    out[row * 256 + t] = f2bf(d * rsqrtf(var + 1e-5f));
}

__global__ __launch_bounds__(256) void k_ln_f32(const float* __restrict__ x, bf16* __restrict__ out)
{
    __shared__ float lds[8];
    const long row = blockIdx.x;
    const int t = threadIdx.x;
    float v = x[row * 256 + t];
    float sm = v;
    #pragma unroll
    for (int o = 32; o; o >>= 1) sm += __shfl_down(sm, o, 64);
    if ((t & 63) == 0) lds[t >> 6] = sm;
    __syncthreads();
    float mean = (lds[0] + lds[1] + lds[2] + lds[3]) * (1.f / 256.f);
    float d = v - mean;
    float qv = d * d;
    #pragma unroll
    for (int o = 32; o; o >>= 1) qv += __shfl_down(qv, o, 64);
    if ((t & 63) == 0) lds[4 + (t >> 6)] = qv;
    __syncthreads();
    float var = (lds[4] + lds[5] + lds[6] + lds[7]) * (1.f / 256.f);
    out[row * 256 + t] = f2bf(d * rsqrtf(var + 1e-5f));
}

// encoder attention, r=0 row only. block = one t, wave = one head.
__global__ __launch_bounds__(256) void k_attn(
    const bf16* __restrict__ q, const bf16* __restrict__ k,
    const bf16* __restrict__ v, bf16* __restrict__ o0)
{
    const long t = blockIdx.x;
    const int h = threadIdx.x >> 6;
    const int lane = threadIdx.x & 63;
    const int s = lane >> 3;
    const int dg = lane & 7;
    const bf16* qp = q + t * 256 + h * 64 + dg * 8;
    const bf16* kp = k + (t * 8 + s) * 256 + h * 64 + dg * 8;
    float p = 0.f;
    #pragma unroll
    for (int e = 0; e < 8; ++e) p += bf2f(qp[e]) * bf2f(kp[e]);
    p += __shfl_xor(p, 1, 64);
    p += __shfl_xor(p, 2, 64);
    p += __shfl_xor(p, 4, 64);
    float sc = p * 0.125f;
    float w[8];
    float mx = -1e30f;
    #pragma unroll
    for (int s2 = 0; s2 < 8; ++s2) { w[s2] = __shfl(sc, s2 * 8, 64); mx = fmaxf(mx, w[s2]); }
    float sum = 0.f;
    #pragma unroll
    for (int s2 = 0; s2 < 8; ++s2) { w[s2] = __expf(w[s2] - mx); sum += w[s2]; }
    float rs = 1.f / sum;
    float acc = 0.f;
    const bf16* vp = v + (t * 8) * 256 + h * 64 + lane;
    #pragma unroll
    for (int s2 = 0; s2 < 8; ++s2) acc += w[s2] * bf2f(vp[(long)s2 * 256]);
    o0[t * 256 + h * 64 + lane] = f2bf(acc * rs);
}

__global__ __launch_bounds__(256) void k_nodes(
    const float* __restrict__ tracks, const float* __restrict__ dets,
    const int* __restrict__ tm, const int* __restrict__ dm,
    float4* __restrict__ nodes)
{
    int idx = blockIdx.x * 256 + threadIdx.x;
    int b = idx >> 10;
    int i = idx & 1023;
    float x, y;
    int valid;
    if (i < 512) {
        long o = (long)(b * 512 + i) * 32;
        x = tracks[o]; y = tracks[o + 1];
        valid = (i < tm[b]) ? 1 : 0;
    } else {
        int n = i - 512;
        long o = (long)(b * 512 + n) * 4;
        x = dets[o]; y = dets[o + 1];
        valid = (n < dm[b]) ? 1 : 0;
    }
    nodes[idx] = make_float4(x, y, valid ? 0.f : 1e9f, 0.f);
}

// GAT src/dst dots from hgT (coalesced along nodes)
__global__ __launch_bounds__(256) void k_srcdst_T(
    const bf16* __restrict__ hgT, const float* __restrict__ av,
    float* __restrict__ src, float* __restrict__ dst, int nN, int nLog)
{
    __shared__ float avs[512];
    const int t = threadIdx.x;
    avs[t] = av[t]; avs[256 + t] = av[256 + t];
    __syncthreads();
    int n = blockIdx.x * 256 + t;
    int b = n >> nLog;
    int j = n & (nN - 1);
    const bf16* base = hgT + ((long)b << (8 + nLog)) + j;
    #pragma unroll
    for (int h = 0; h < 4; ++h) {
        float p0 = 0.f, p1 = 0.f;
        for (int dd = 0; dd < 64; ++dd) {
            int d = h * 64 + dd;
            float v = bf2f(base[(long)d << nLog]);
            p0 += v * avs[d];
            p1 += v * avs[256 + d];
        }
        src[(long)n * 4 + h] = p0;
        dst[(long)n * 4 + h] = p1;
    }
}

// GAT softmax stats (m,s) per (b,i), 4 heads — unchanged from R3
__global__ __launch_bounds__(256) void k_gatms(
    const float4* __restrict__ nodes,
    const float4* __restrict__ srcv, const float4* __restrict__ dstv,
    float4* __restrict__ m4, float4* __restrict__ s4,
    int nN, int nodeOfs)
{
    const int bi = blockIdx.x;
    const int b = bi / nN;
    const int i = bi - b * nN;
    const float4* nb = nodes + b * 1024 + nodeOfs;
    const float4 ni = nb[i];
    const float4 si = srcv[bi];
    float mv[4] = {-1e9f, -1e9f, -1e9f, -1e9f};
    float sv[4] = {0.f, 0.f, 0.f, 0.f};
    for (int j = threadIdx.x; j < nN; j += 256) {
        float4 nj = nb[j];
        bool adj = node_adj(ni, nj);
        float4 dj = dstv[(long)b * nN + j];
        float e[4];
        e[0] = si.x + dj.x; e[1] = si.y + dj.y; e[2] = si.z + dj.z; e[3] = si.w + dj.w;
        #pragma unroll
        for (int h = 0; h < 4; ++h) {
            float eh = e[h] >= 0.f ? e[h] : 0.2f * e[h];
            eh = adj ? eh : -1e9f;
            float nm = fmaxf(mv[h], eh);
            sv[h] = sv[h] * __expf(fminf(mv[h] - nm, 0.f)) + __expf(fminf(eh - nm, 0.f));
            mv[h] = nm;
        }
    }
    __shared__ float rm[4][256];
    __shared__ float rs[4][256];
    #pragma unroll
    for (int h = 0; h < 4; ++h) { rm[h][threadIdx.x] = mv[h]; rs[h][threadIdx.x] = sv[h]; }
    __syncthreads();
    for (int off = 128; off >= 1; off >>= 1) {
        if ((int)threadIdx.x < off) {
            #pragma unroll
            for (int h = 0; h < 4; ++h) {
                float ma = rm[h][threadIdx.x], mb2 = rm[h][threadIdx.x + off];
                float sa = rs[h][threadIdx.x], sb2 = rs[h][threadIdx.x + off];
                float nm = fmaxf(ma, mb2);
                rm[h][threadIdx.x] = nm;
                rs[h][threadIdx.x] = sa * __expf(fminf(ma - nm, 0.f)) + sb2 * __expf(fminf(mb2 - nm, 0.f));
            }
        }
        __syncthreads();
    }
    if (threadIdx.x == 0) {
        m4[bi] = make_float4(rm[0][0], rm[1][0], rm[2][0], rm[3][0]);
        s4[bi] = make_float4(rs[0][0], rs[1][0], rs[2][0], rs[3][0]);
    }
}

// GAT aggregation as MFMA GEMM. Block = (b, 32 i-rows); wave = head.
// O[i,d] = sum_j exp(e_h(i,j)-m_i) * hgT[d][j]; epilogue: /s_i, elu, residual.
__global__ __launch_bounds__(256) void k_gatagg_mm(
    const bf16* __restrict__ hgT,
    const unsigned long long* __restrict__ adjm,
    const float4* __restrict__ srcv, const float4* __restrict__ m4,
    const float4* __restrict__ s4, const float4* __restrict__ dstv,
    const float* __restrict__ res, int resBatchStride,
    bf16* __restrict__ outb, int nN)
{
    __shared__ float dstT[4][1024];
    __shared__ unsigned int adjW[32][33];
    const int t = threadIdx.x;
    const int nblk = nN >> 5;
    const int b = blockIdx.x / nblk;
    const int i0 = (blockIdx.x - b * nblk) << 5;
    const int nC = nN >> 6;
    for (int j = t; j < nN; j += 256) {
        float4 dj = dstv[(long)b * nN + j];
        dstT[0][j] = dj.x; dstT[1][j] = dj.y; dstT[2][j] = dj.z; dstT[3][j] = dj.w;
    }
    for (int idx = t; idx < 32 * nC; idx += 256) {
        int r = idx / nC, c = idx - r * nC;
        unsigned long long v = adjm[((long)b * nN + i0 + r) * nC + c];
        adjW[r][c * 2] = (unsigned)v;
        adjW[r][c * 2 + 1] = (unsigned)(v >> 32);
    }
    __syncthreads();
    const int h = t >> 6, lane = t & 63, lr = lane & 15, kq = lane >> 4;
    float s_r[2], m_r[2];
    #pragma unroll
    for (int mt = 0; mt < 2; ++mt) {
        long idx = (long)b * nN + i0 + mt * 16 + lr;
        s_r[mt] = ((const float*)(srcv + idx))[h];
        m_r[mt] = ((const float*)(m4 + idx))[h];
    }
    f32x4 acc[2][4] = {};
    const bf16* hb = hgT + ((long)b * 256 + h * 64) * nN;
    for (int j0 = 0; j0 < nN; j0 += 32) {
        bf16x8 bfr[4];
        #pragma unroll
        for (int nt = 0; nt < 4; ++nt)
            bfr[nt] = *(const bf16x8*)(hb + (long)(nt * 16 + lr) * nN + j0 + kq * 8);
        #pragma unroll
        for (int mt = 0; mt < 2; ++mt) {
            unsigned byte = (adjW[mt * 16 + lr][j0 >> 5] >> (kq * 8)) & 0xffu;
            bf16x8 af;
            #pragma unroll
            for (int jj = 0; jj < 8; ++jj) {
                float e = s_r[mt] + dstT[h][j0 + kq * 8 + jj];
                e = fmaxf(e, 0.2f * e);                    // leaky_relu(e, 0.2)
                e = (byte & (1u << jj)) ? e : -1e9f;
                af[jj] = f2bf(__expf(e - m_r[mt]));
            }
            #pragma unroll
            for (int nt = 0; nt < 4; ++nt)
                acc[mt][nt] = __builtin_amdgcn_mfma_f32_16x16x32_bf16(af, bfr[nt], acc[mt][nt], 0, 0, 0);
        }
    }
    #pragma unroll
    for (int mt = 0; mt < 2; ++mt) {
        #pragma unroll
        for (int ii = 0; ii < 4; ++ii) {
            int i = i0 + mt * 16 + kq * 4 + ii;
            long bi = (long)b * nN + i;
            float rs = 1.f / fmaxf(((const float*)(s4 + bi))[h], 1e-30f);
            #pragma unroll
            for (int nt = 0; nt < 4; ++nt) {
                int col = h * 64 + nt * 16 + lr;
                float a = acc[mt][nt][ii] * rs;
                float e = a > 0.f ? a : expm1f(a);
                float v = 0.5f * e + 0.5f * res[(long)b * resBatchStride + (long)i * 256 + col];
                outb[bi * 256 + col] = f2bf(v);
            }
        }
    }
}

// ---------------------------------------------------------------------------
extern "C" void kernel_launch(void* const* d_in, const int* in_sizes, int n_in,
                              void* d_out, int out_size, void* d_ws, size_t ws_size,
                              hipStream_t stream)
{
    (void)in_sizes; (void)n_in; (void)out_size; (void)ws_size;
    const float* tracks = (const float*)d_in[0];
    const float* dets   = (const float*)d_in[1];
    const int*  tmarks = (const int*)d_in[2];
    const int*  dmarks = (const int*)d_in[3];
    const float* W1   = (const float*)d_in[4];
    const float* b1   = (const float*)d_in[5];
    const float* W2   = (const float*)d_in[6];
    const float* b2   = (const float*)d_in[7];
    const float* Wqkv = (const float*)d_in[8];
    const float* Wo   = (const float*)d_in[9];
    const float* eff1 = (const float*)d_in[10];
    const float* eff2 = (const float*)d_in[11];
    const float* gatW = (const float*)d_in[12];
    const float* gatA = (const float*)d_in[13];
    const float* dgatW = (const float*)d_in[14];
    const float* dgatA = (const float*)d_in[15];
    const float* clsWq = (const float*)d_in[16];
    const float* clsWk = (const float*)d_in[17];
    float* out = (float*)d_out;

    char* wsb = (char*)d_ws;
    size_t off = 0;
    auto take = [&](size_t bytes) -> char* {
        char* p = wsb + off;
        off += (bytes + 255) & ~(size_t)255;
        return p;
    };
    char* R_emb  = take(37748736);   // emb_b; later x20(+0), h2_b(+8388608)
    char* R_r0   = take(8388608);    // emb_r0_f
    char* R_hln  = take(33554432);   // hln; later f1_b
    char* R_v    = take(33554432);   // v_b; later xq_b(+0), xk_b(+8388608)
    char* R_gat  = take(25165824);   // hgT(+0), xga_b(+8388608), xgb_b(+16777216)
    char* R_q    = take(4194304);    // q_b
    char* R_o0   = take(4194304);    // o0_b
    char* R_f0f  = take(16777216);   // feat0_f
    char* R_f0b  = take(8388608);    // feat0_b
    char* R_demb = take(4194304);    // demb_b
    float4* nodes = (float4*)take(262144);
    float4* src4  = (float4*)take(262144);
    float4* dst4  = (float4*)take(262144);
    float4* m4    = (float4*)take(262144);
    float4* s4    = (float4*)take(262144);
    unsigned long long* adjm_main = (unsigned long long*)take(2097152);
    unsigned long long* adjm_det  = (unsigned long long*)take(524288);

    bf16*  emb_b    = (bf16*)R_emb;
    float* emb_r0_f = (float*)R_r0;
    bf16*  hln      = (bf16*)R_hln;
    bf16*  v_b      = (bf16*)R_v;
    bf16*  k_b      = (bf16*)d_out;         // scratch in d_out; dead before logits
    bf16*  q_b      = (bf16*)R_q;
    bf16*  o0_b     = (bf16*)R_o0;
    float* x20      = (float*)R_emb;
    bf16*  h2_b     = (bf16*)(R_emb + 8388608);
    bf16*  f1_b     = (bf16*)R_hln;
    float* feat0_f  = (float*)R_f0f;
    bf16*  feat0_b  = (bf16*)R_f0b;
    bf16*  demb_b   = (bf16*)R_demb;
    bf16*  hgT      = (bf16*)R_gat;
    bf16*  xga_b    = (bf16*)(R_gat + 8388608);
    bf16*  xgb_b    = (bf16*)(R_gat + 16777216);
    bf16*  xq_b     = (bf16*)R_v;
    bf16*  xk_b     = (bf16*)(R_v + 8388608);

    // graph + adjacency masks + embeddings
    k_nodes<<<64, 256, 0, stream>>>(tracks, dets, tmarks, dmarks, nodes);
    k_adjmask<<<16384, 256, 0, stream>>>(nodes, adjm_main, 1024, 10, 0);
    k_adjmask<<<8192, 256, 0, stream>>>(nodes, adjm_det, 512, 9, 512);
    k_featgemm<<<dim3(4, 1152, 1), 256, 0, stream>>>(tracks, dets, W1, b1, W2, b2,
        emb_b, emb_r0_f, feat0_f, feat0_b, demb_b);

    // encoder (only r=0 row needed downstream of attention)
    k_ln_bf16<<<65536, 256, 0, stream>>>(emb_b, hln);
    k_gemm_bf16<<<dim3(4, 1024, 1), 256, 0, stream>>>(hln, 256, Wqkv + 256, 768, k_b, 256, 256, 0);
    k_gemm_bf16<<<dim3(4, 1024, 1), 256, 0, stream>>>(hln, 256, Wqkv + 512, 768, v_b, 256, 256, 0);
    k_gemm_bf16<<<dim3(4, 128, 1), 256, 0, stream>>>(hln, 2048, Wqkv, 768, q_b, 256, 256, 0);
    k_attn<<<8192, 256, 0, stream>>>(q_b, k_b, v_b, o0_b);
    k_gemm_addres<<<dim3(4, 128, 1), 256, 0, stream>>>(o0_b, 256, Wo, 256, emb_r0_f, 256, x20, 256, 256);
    k_ln_f32<<<8192, 256, 0, stream>>>(x20, h2_b);
    k_gemm_bf16<<<dim3(16, 128, 1), 256, 0, stream>>>(h2_b, 256, eff1, 1024, f1_b, 1024, 256, 1);
    k_gemm_pred<<<dim3(4, 128, 1), 256, 0, stream>>>(f1_b, 1024, eff2, 256, emb_r0_f, x20, feat0_f, feat0_b, 1024);

    // main GAT layer 1
    k_gemm_T<<<dim3(256, 4, 1), 256, 0, stream>>>(feat0_b, gatW, hgT, 1024, 10);
    k_srcdst_T<<<64, 256, 0, stream>>>(hgT, gatA, (float*)src4, (float*)dst4, 1024, 10);
    k_gatms<<<16384, 256, 0, stream>>>(nodes, src4, dst4, m4, s4, 1024, 0);
    k_gatagg_mm<<<512, 256, 0, stream>>>(hgT, adjm_main, src4, m4, s4, dst4,
        feat0_f, 262144, xga_b, 1024);
    // main GAT layer 2
    k_gemm_T<<<dim3(256, 4, 1), 256, 0, stream>>>(xga_b, gatW + 65536, hgT, 1024, 10);
    k_srcdst_T<<<64, 256, 0, stream>>>(hgT, gatA + 512, (float*)src4, (float*)dst4, 1024, 10);
    k_gatms<<<16384, 256, 0, stream>>>(nodes, src4, dst4, m4, s4, 1024, 0);
    k_gatagg_mm<<<512, 256, 0, stream>>>(hgT, adjm_main, src4, m4, s4, dst4,
        feat0_f, 262144, xgb_b, 1024);
    // main scores + asso
    k_gemm_bf16<<<dim3(4, 256, 1), 256, 0, stream>>>(xgb_b, 256, clsWq, 256, xq_b, 256, 256, 0);
    k_gemm_bf16<<<dim3(4, 256, 1), 256, 0, stream>>>(xgb_b, 256, clsWk, 256, xk_b, 256, 256, 0);
    k_gemm_logits<<<dim3(16, 16, 16), 256, 0, stream>>>(xq_b, 262144L, xk_b, 262144L, 256,
        out, 1024, 1048576L, nodes, 0, out + 20971520L, 1);

    // det branch
    k_gemm_T<<<dim3(128, 4, 1), 256, 0, stream>>>(demb_b, dgatW, hgT, 512, 9);
    k_srcdst_T<<<32, 256, 0, stream>>>(hgT, dgatA, (float*)src4, (float*)dst4, 512, 9);
    k_gatms<<<8192, 256, 0, stream>>>(nodes, src4, dst4, m4, s4, 512, 512);
    k_gatagg_mm<<<256, 256, 0, stream>>>(hgT, adjm_det, src4, m4, s4, dst4,
        feat0_f + 131072, 262144, xga_b, 512);
    k_gemm_T<<<dim3(128, 4, 1), 256, 0, stream>>>(xga_b, dgatW + 65536, hgT, 512, 9);
    k_srcdst_T<<<32, 256, 0, stream>>>(hgT, dgatA + 512, (float*)src4, (float*)dst4, 512, 9);
    k_gatms<<<8192, 256, 0, stream>>>(nodes, src4, dst4, m4, s4, 512, 512);
    k_gatagg_mm<<<256, 256, 0, stream>>>(hgT, adjm_det, src4, m4, s4, dst4,
        feat0_f + 131072, 262144, xgb_b, 512);
    k_gemm_bf16<<<dim3(4, 128, 1), 256, 0, stream>>>(xgb_b, 256, clsWq + 65536, 256, xq_b, 256, 256, 0);
    k_gemm_bf16<<<dim3(4, 128, 1), 256, 0, stream>>>(xgb_b, 256, clsWk + 65536, 256, xk_b, 256, 256, 0);
    k_gemm_logits<<<dim3(8, 8, 16), 256, 0, stream>>>(xq_b, 131072L, xk_b, 131072L, 256,
        out + 16777216L, 512, 262144L, nodes, 512, (float*)nullptr, 2);
}

// Round 5
// 708.818 us; speedup vs baseline: 3.2210x; 1.3421x over previous
//
#include <hip/hip_runtime.h>
#include <math.h>

// ScatterNet_21706764714521 — round 5: pre-transposed bf16 weights (k_prep),
// wide-N featgemm, 2-phase gatms, wave-per-row LN, wider srcdst.
// fp32 I/O, bf16 MFMA internally. Workspace ~184 MB (+33.5 MB d_out scratch).

typedef __bf16 bf16;
typedef __bf16 bf16x8 __attribute__((ext_vector_type(8)));
typedef __bf16 bf16x4 __attribute__((ext_vector_type(4)));
typedef float f32x4 __attribute__((ext_vector_type(4)));

__device__ __forceinline__ float bf2f(bf16 x) { return (float)x; }
__device__ __forceinline__ bf16 f2bf(float x) { return (bf16)x; }

// node record: (x, y, invalid?1e9:0, 0). adjacency = dist<2 && both valid.
__device__ __forceinline__ bool node_adj(float4 a, float4 c) {
    float dx = a.x - c.x, dy = a.y - c.y;
    return (sqrtf(dx * dx + dy * dy) + a.z + c.z) < 2.0f;
}

// ---------------------------------------------------------------------------
// Weight prep: transpose+convert fp32 [R][C] -> bf16 [C][R], 32x32 tiles.
// ---------------------------------------------------------------------------
struct PrepEnt { const float* src; long dofs; int R; int C; int tstart; };
struct PrepTab { PrepEnt e[13]; };

__global__ __launch_bounds__(256) void k_prep(PrepTab tab, bf16* __restrict__ dst)
{
    __shared__ float tile[32][33];
    const int tid = blockIdx.x;
    int k = 0;
    #pragma unroll
    for (int q = 1; q < 13; ++q) if (tid >= tab.e[q].tstart) k = q;
    PrepEnt E = tab.e[k];
    const int local = tid - E.tstart;
    const int cT = E.C >> 5;
    const int tr = local / cT, tc = local - tr * cT;
    const int r0 = tr << 5, c0 = tc << 5;
    const int t = threadIdx.x;
    {
        int r = t >> 3, cq = (t & 7) * 4;
        *(float4*)&tile[r][cq] = *(const float4*)(E.src + (long)(r0 + r) * E.C + c0 + cq);
    }
    __syncthreads();
    {
        int c = t >> 3, rq = (t & 7) * 4;
        bf16x4 o;
        o[0] = f2bf(tile[rq + 0][c]); o[1] = f2bf(tile[rq + 1][c]);
        o[2] = f2bf(tile[rq + 2][c]); o[3] = f2bf(tile[rq + 3][c]);
        *(bf16x4*)(dst + E.dofs + (long)(c0 + c) * E.R + r0 + rq) = o;
    }
}

// ---------------------------------------------------------------------------
// MFMA GEMM core: C(64x64/block) = A(MxK) @ BT(NxK)^T, bf16 in, fp32 acc.
// Both operands row-major-in-K -> pure uint4 staging.
// D mapping: row = m0 + wv*16 + kq*4 + i, col = n0 + nt*16 + lr.
// ---------------------------------------------------------------------------
__device__ __forceinline__ void gemm_bt(const bf16* __restrict__ A, int lda,
                                        const bf16* __restrict__ BT, int ldb,
                                        int K, f32x4 acc[4])
{
    __shared__ bf16 As[64][40];
    __shared__ bf16 Bs[64][40];
    const int t = threadIdx.x;
    const int m0 = blockIdx.y * 64;
    const int n0 = blockIdx.x * 64;
    const int lane = t & 63, wv = t >> 6, lr = lane & 15, kq = lane >> 4;
    const int arow = t >> 2, acol = (t & 3) * 8;
    for (int k0 = 0; k0 < K; k0 += 32) {
        __syncthreads();
        *(uint4*)&As[arow][acol] = *(const uint4*)(A + (long)(m0 + arow) * lda + k0 + acol);
        *(uint4*)&Bs[arow][acol] = *(const uint4*)(BT + (long)(n0 + arow) * ldb + k0 + acol);
        __syncthreads();
        bf16x8 af = *(const bf16x8*)&As[wv * 16 + lr][kq * 8];
        #pragma unroll
        for (int nt = 0; nt < 4; ++nt) {
            bf16x8 bfr = *(const bf16x8*)&Bs[nt * 16 + lr][kq * 8];
            acc[nt] = __builtin_amdgcn_mfma_f32_16x16x32_bf16(af, bfr, acc[nt], 0, 0, 0);
        }
    }
}

__global__ __launch_bounds__(256) void k_gemm_bf16(
    const bf16* __restrict__ A, int lda,
    const bf16* __restrict__ BT, int ldb,
    bf16* __restrict__ out, int ldo, int K, int relu)
{
    f32x4 acc[4] = {};
    gemm_bt(A, lda, BT, ldb, K, acc);
    const int lane = threadIdx.x & 63, wv = threadIdx.x >> 6;
    const int lr = lane & 15, kq = lane >> 4;
    const int m0 = blockIdx.y * 64, n0 = blockIdx.x * 64;
    #pragma unroll
    for (int nt = 0; nt < 4; ++nt) {
        int col = n0 + nt * 16 + lr;
        #pragma unroll
        for (int i = 0; i < 4; ++i) {
            int row = m0 + wv * 16 + kq * 4 + i;
            float v = acc[nt][i];
            if (relu) v = fmaxf(v, 0.f);
            out[(long)row * ldo + col] = f2bf(v);
        }
    }
}

// out = res1 + acc (fp32 out)
__global__ __launch_bounds__(256) void k_gemm_addres(
    const bf16* __restrict__ A, int lda,
    const bf16* __restrict__ BT, int ldb,
    const float* __restrict__ res1, int ldr1,
    float* __restrict__ outf, int ldo, int K)
{
    f32x4 acc[4] = {};
    gemm_bt(A, lda, BT, ldb, K, acc);
    const int lane = threadIdx.x & 63, wv = threadIdx.x >> 6;
    const int lr = lane & 15, kq = lane >> 4;
    const int m0 = blockIdx.y * 64, n0 = blockIdx.x * 64;
    #pragma unroll
    for (int nt = 0; nt < 4; ++nt) {
        int col = n0 + nt * 16 + lr;
        #pragma unroll
        for (int i = 0; i < 4; ++i) {
            int row = m0 + wv * 16 + kq * 4 + i;
            outf[(long)row * ldo + col] = res1[(long)row * ldr1 + col] + acc[nt][i];
        }
    }
}

// predicted = tr_emb0 + 0.9*(x2_0 + ff2_out); scattered to feat0[b*1024+m]
__global__ __launch_bounds__(256) void k_gemm_pred(
    const bf16* __restrict__ A, int lda,
    const bf16* __restrict__ BT, int ldb,
    const float* __restrict__ res1, const float* __restrict__ res2,
    float* __restrict__ outf, bf16* __restrict__ outb, int K)
{
    f32x4 acc[4] = {};
    gemm_bt(A, lda, BT, ldb, K, acc);
    const int lane = threadIdx.x & 63, wv = threadIdx.x >> 6;
    const int lr = lane & 15, kq = lane >> 4;
    const int m0 = blockIdx.y * 64, n0 = blockIdx.x * 64;
    #pragma unroll
    for (int nt = 0; nt < 4; ++nt) {
        int col = n0 + nt * 16 + lr;
        #pragma unroll
        for (int i = 0; i < 4; ++i) {
            int row = m0 + wv * 16 + kq * 4 + i;     // b*512 + m
            float v = res1[(long)row * 256 + col]
                    + 0.9f * (res2[(long)row * 256 + col] + acc[nt][i]);
            long drow = (long)row + ((row >> 9) << 9);   // b*1024 + m
            long o = drow * 256 + col;
            outf[o] = v;
            outb[o] = f2bf(v);
        }
    }
}

// scores = sigmoid(acc/16) * adj (fp32 out); optional asso copy / zero diag
__global__ __launch_bounds__(256) void k_gemm_logits(
    const bf16* __restrict__ A, long sAz,
    const bf16* __restrict__ Bm, long sBz, int K,
    float* __restrict__ out, int ldo, long sOz,
    const float4* __restrict__ nodes, int nodeOfs,
    float* __restrict__ asso, int flags)
{
    f32x4 acc[4] = {};
    const int z = blockIdx.z;
    gemm_bt(A + z * sAz, 256, Bm + z * sBz, 256, K, acc);
    const int lane = threadIdx.x & 63, wv = threadIdx.x >> 6;
    const int lr = lane & 15, kq = lane >> 4;
    const int m0 = blockIdx.y * 64, n0 = blockIdx.x * 64;
    const float4* nb = nodes + z * 1024 + nodeOfs;
    float4 nrow[4], ncol[4];
    #pragma unroll
    for (int i = 0; i < 4; ++i) nrow[i] = nb[m0 + wv * 16 + kq * 4 + i];
    #pragma unroll
    for (int nt = 0; nt < 4; ++nt) ncol[nt] = nb[n0 + nt * 16 + lr];
    float* ob = out + z * sOz;
    #pragma unroll
    for (int nt = 0; nt < 4; ++nt) {
        int col = n0 + nt * 16 + lr;
        #pragma unroll
        for (int i = 0; i < 4; ++i) {
            int row = m0 + wv * 16 + kq * 4 + i;
            bool adj = node_adj(nrow[i], ncol[nt]);
            if ((flags & 2) && row == col) adj = false;
            float v = 0.f;
            if (adj) v = 1.f / (1.f + __expf(-acc[nt][i] * 0.0625f));
            ob[(long)row * ldo + col] = v;
            if ((flags & 1) && row < 512 && col >= 512)
                asso[(long)z * 262144 + (long)row * 512 + (col - 512)] = v;
        }
    }
}

// GAT projection, transposed output: hgT[b][d][j] = (X @ W)[b*nN+j][d]
__global__ __launch_bounds__(256) void k_gemm_T(
    const bf16* __restrict__ WT, const bf16* __restrict__ X,
    bf16* __restrict__ hgT, int nN, int nLog)
{
    f32x4 acc[4] = {};
    gemm_bt(WT, 256, X, 256, 256, acc);   // m = dout (blockIdx.y), n = node (blockIdx.x)
    const int lane = threadIdx.x & 63, wv = threadIdx.x >> 6;
    const int lr = lane & 15, kq = lane >> 4;
    const int d0 = blockIdx.y * 64, n0 = blockIdx.x * 64;
    #pragma unroll
    for (int nt = 0; nt < 4; ++nt) {
        int node = n0 + nt * 16 + lr;
        int b = node >> nLog;
        int j = node & (nN - 1);
        #pragma unroll
        for (int i = 0; i < 4; ++i) {
            int d = d0 + wv * 16 + kq * 4 + i;
            hgT[((long)(b * 256 + d) << nLog) + j] = f2bf(acc[nt][i]);
        }
    }
}

// ---------------------------------------------------------------------------
// fused feat MLP, wide-N: block = 64 rows x all 256 cols.
// ---------------------------------------------------------------------------
__global__ __launch_bounds__(256) void k_featgemm(
    const float* __restrict__ tracks, const float* __restrict__ dets,
    const float* __restrict__ W1, const float* __restrict__ b1,
    const bf16* __restrict__ W2T, const float* __restrict__ b2,
    bf16* __restrict__ emb_b, float* __restrict__ emb_r0_f,
    float* __restrict__ feat0_f, bf16* __restrict__ feat0_b,
    bf16* __restrict__ demb_b)
{
    __shared__ float xr[64][4];
    __shared__ float w1s[4][256];
    __shared__ float b1s[256];
    __shared__ bf16 As[64][40];
    __shared__ bf16 Bs[256][40];
    const int t = threadIdx.x;
    const int m0 = blockIdx.x * 64;
    if (t < 64) {
        int gr = m0 + t;
        const float* sp = (gr < 65536) ? (tracks + (long)gr * 4)
                                       : (dets + (long)(gr - 65536) * 4);
        *(float4*)&xr[t][0] = *(const float4*)sp;
    }
    w1s[0][t] = W1[t];       w1s[1][t] = W1[256 + t];
    w1s[2][t] = W1[512 + t]; w1s[3][t] = W1[768 + t];
    b1s[t] = b1[t];
    const int arow = t >> 2, acol = (t & 3) * 8;
    const int lane = t & 63, wv = t >> 6, lr = lane & 15, kq = lane >> 4;
    f32x4 acc[16] = {};
    __syncthreads();
    for (int k0 = 0; k0 < 256; k0 += 32) {
        __syncthreads();
        #pragma unroll
        for (int j = 0; j < 8; ++j) {
            int c = k0 + acol + j;
            float v = fmaf(xr[arow][0], w1s[0][c],
                      fmaf(xr[arow][1], w1s[1][c],
                      fmaf(xr[arow][2], w1s[2][c],
                      fmaf(xr[arow][3], w1s[3][c], b1s[c]))));
            v = v > 0.f ? v : (__expf(v) - 1.f);
            As[arow][acol + j] = f2bf(v);
        }
        #pragma unroll
        for (int rr = 0; rr < 4; ++rr) {
            int n = rr * 64 + (t >> 2);
            *(uint4*)&Bs[n][acol] = *(const uint4*)(W2T + (long)n * 256 + k0 + acol);
        }
        __syncthreads();
        bf16x8 af = *(const bf16x8*)&As[wv * 16 + lr][kq * 8];
        #pragma unroll
        for (int nt = 0; nt < 16; ++nt) {
            bf16x8 bfr = *(const bf16x8*)&Bs[nt * 16 + lr][kq * 8];
            acc[nt] = __builtin_amdgcn_mfma_f32_16x16x32_bf16(af, bfr, acc[nt], 0, 0, 0);
        }
    }
    #pragma unroll
    for (int nt = 0; nt < 16; ++nt) {
        int col = nt * 16 + lr;
        float bv = b2[col];
        #pragma unroll
        for (int i = 0; i < 4; ++i) {
            int gr = m0 + wv * 16 + kq * 4 + i;
            float v = acc[nt][i] + bv;
            emb_b[(long)gr * 256 + col] = f2bf(v);
            if (gr < 65536) {
                if ((gr & 7) == 0) emb_r0_f[(long)(gr >> 3) * 256 + col] = v;
            } else {
                int dr = gr - 65536;
                long drow = ((long)(dr >> 9) << 10) + 512 + (dr & 511);
                feat0_f[drow * 256 + col] = v;
                feat0_b[drow * 256 + col] = f2bf(v);
                demb_b[(long)dr * 256 + col] = f2bf(v);
            }
        }
    }
}

// adjacency bitmask rows via ballot
__global__ __launch_bounds__(256) void k_adjmask(
    const float4* __restrict__ nodes, unsigned long long* __restrict__ adjm,
    int nN, int nLog, int nodeOfs)
{
    const int bi = blockIdx.x;
    const int b = bi >> nLog;
    const int i = bi & (nN - 1);
    const float4* nb = nodes + b * 1024 + nodeOfs;
    const float4 ni = nb[i];
    const int t = threadIdx.x;
    const int w = t >> 6, lane = t & 63;
    const int nC = nN >> 6;
    for (int it = 0; it * 256 < nN; ++it) {
        int j = it * 256 + t;
        bool adj = node_adj(ni, nb[j]);
        unsigned long long mask = __ballot(adj);
        if (lane == 0) adjm[(long)bi * nC + it * 4 + w] = mask;
    }
}

// LayerNorm wave-per-row (4 rows/block), bf16 in -> bf16 out
__global__ __launch_bounds__(256) void k_ln_bf16(const bf16* __restrict__ x, bf16* __restrict__ out)
{
    const int w = threadIdx.x >> 6, l = threadIdx.x & 63;
    const long row = (long)blockIdx.x * 4 + w;
    bf16x4 xv = *(const bf16x4*)(x + row * 256 + l * 4);
    float v0 = bf2f(xv[0]), v1 = bf2f(xv[1]), v2 = bf2f(xv[2]), v3 = bf2f(xv[3]);
    float s = v0 + v1 + v2 + v3;
    #pragma unroll
    for (int o = 32; o; o >>= 1) s += __shfl_xor(s, o, 64);
    float mean = s * (1.f / 256.f);
    float d0 = v0 - mean, d1 = v1 - mean, d2 = v2 - mean, d3 = v3 - mean;
    float q = d0 * d0 + d1 * d1 + d2 * d2 + d3 * d3;
    #pragma unroll
    for (int o = 32; o; o >>= 1) q += __shfl_xor(q, o, 64);
    float rstd = rsqrtf(q * (1.f / 256.f) + 1e-5f);
    bf16x4 ov;
    ov[0] = f2bf(d0 * rstd); ov[1] = f2bf(d1 * rstd);
    ov[2] = f2bf(d2 * rstd); ov[3] = f2bf(d3 * rstd);
    *(bf16x4*)(out + row * 256 + l * 4) = ov;
}

__global__ __launch_bounds__(256) void k_ln_f32(const float* __restrict__ x, bf16* __restrict__ out)
{
    const int w = threadIdx.x >> 6, l = threadIdx.x & 63;
    const long row = (long)blockIdx.x * 4 + w;
    float4 xv = *(const float4*)(x + row * 256 + l * 4);
    float s = xv.x + xv.y + xv.z + xv.w;
    #pragma unroll
    for (int o = 32; o; o >>= 1) s += __shfl_xor(s, o, 64);
    float mean = s * (1.f / 256.f);
    float d0 = xv.x - mean, d1 = xv.y - mean, d2 = xv.z - mean, d3 = xv.w - mean;
    float q = d0 * d0 + d1 * d1 + d2 * d2 + d3 * d3;
    #pragma unroll
    for (int o = 32; o; o >>= 1) q += __shfl_xor(q, o, 64);
    float rstd = rsqrtf(q * (1.f / 256.f) + 1e-5f);
    bf16x4 ov;
    ov[0] = f2bf(d0 * rstd); ov[1] = f2bf(d1 * rstd);
    ov[2] = f2bf(d2 * rstd); ov[3] = f2bf(d3 * rstd);
    *(bf16x4*)(out + row * 256 + l * 4) = ov;
}

// encoder attention, r=0 row only. block = one t, wave = one head.
__global__ __launch_bounds__(256) void k_attn(
    const bf16* __restrict__ q, const bf16* __restrict__ k,
    const bf16* __restrict__ v, bf16* __restrict__ o0)
{
    const long t = blockIdx.x;
    const int h = threadIdx.x >> 6;
    const int lane = threadIdx.x & 63;
    const int s = lane >> 3;
    const int dg = lane & 7;
    const bf16* qp = q + t * 256 + h * 64 + dg * 8;
    const bf16* kp = k + (t * 8 + s) * 256 + h * 64 + dg * 8;
    float p = 0.f;
    #pragma unroll
    for (int e = 0; e < 8; ++e) p += bf2f(qp[e]) * bf2f(kp[e]);
    p += __shfl_xor(p, 1, 64);
    p += __shfl_xor(p, 2, 64);
    p += __shfl_xor(p, 4, 64);
    float sc = p * 0.125f;
    float w[8];
    float mx = -1e30f;
    #pragma unroll
    for (int s2 = 0; s2 < 8; ++s2) { w[s2] = __shfl(sc, s2 * 8, 64); mx = fmaxf(mx, w[s2]); }
    float sum = 0.f;
    #pragma unroll
    for (int s2 = 0; s2 < 8; ++s2) { w[s2] = __expf(w[s2] - mx); sum += w[s2]; }
    float rs = 1.f / sum;
    float acc = 0.f;
    const bf16* vp = v + (t * 8) * 256 + h * 64 + lane;
    #pragma unroll
    for (int s2 = 0; s2 < 8; ++s2) acc += w[s2] * bf2f(vp[(long)s2 * 256]);
    o0[t * 256 + h * 64 + lane] = f2bf(acc * rs);
}

__global__ __launch_bounds__(256) void k_nodes(
    const float* __restrict__ tracks, const float* __restrict__ dets,
    const int* __restrict__ tm, const int* __restrict__ dm,
    float4* __restrict__ nodes)
{
    int idx = blockIdx.x * 256 + threadIdx.x;
    int b = idx >> 10;
    int i = idx & 1023;
    float x, y;
    int valid;
    if (i < 512) {
        long o = (long)(b * 512 + i) * 32;
        x = tracks[o]; y = tracks[o + 1];
        valid = (i < tm[b]) ? 1 : 0;
    } else {
        int n = i - 512;
        long o = (long)(b * 512 + n) * 4;
        x = dets[o]; y = dets[o + 1];
        valid = (n < dm[b]) ? 1 : 0;
    }
    nodes[idx] = make_float4(x, y, valid ? 0.f : 1e9f, 0.f);
}

// GAT src/dst dots from hgT; block = 64 nodes x 4 heads
__global__ __launch_bounds__(256) void k_srcdst_T(
    const bf16* __restrict__ hgT, const float* __restrict__ av,
    float* __restrict__ src, float* __restrict__ dst, int nN, int nLog)
{
    __shared__ float avs[512];
    const int t = threadIdx.x;
    avs[t] = av[t]; avs[256 + t] = av[256 + t];
    __syncthreads();
    const int jl = t & 63, h = t >> 6;
    const int n = blockIdx.x * 64 + jl;
    const int b = n >> nLog, j = n & (nN - 1);
    const bf16* base = hgT + (((long)b * 256 + h * 64) << nLog) + j;
    float p0 = 0.f, p1 = 0.f;
    #pragma unroll 8
    for (int dd = 0; dd < 64; ++dd) {
        float v = bf2f(base[(long)dd << nLog]);
        p0 += v * avs[h * 64 + dd];
        p1 += v * avs[256 + h * 64 + dd];
    }
    src[(long)n * 4 + h] = p0;
    dst[(long)n * 4 + h] = p1;
}

// GAT softmax stats, 2-phase (max then sum): 16 exp/thread instead of ~96.
__global__ __launch_bounds__(256) void k_gatms(
    const float4* __restrict__ nodes,
    const float4* __restrict__ srcv, const float4* __restrict__ dstv,
    float4* __restrict__ m4, float4* __restrict__ s4,
    int nN, int nodeOfs)
{
    const int bi = blockIdx.x;
    const int b = bi / nN;
    const int i = bi - b * nN;
    const float4* nb = nodes + b * 1024 + nodeOfs;
    const float4 ni = nb[i];
    const float4 si = srcv[bi];
    const int t = threadIdx.x;
    const int nIter = nN >> 8;
    float cand[4][4];
    float mv0 = -1e9f, mv1 = -1e9f, mv2 = -1e9f, mv3 = -1e9f;
    for (int it = 0; it < nIter; ++it) {
        int j = it * 256 + t;
        bool adj = node_adj(ni, nb[j]);
        float4 dj = dstv[(long)b * nN + j];
        float e0 = si.x + dj.x; e0 = fmaxf(e0, 0.2f * e0); e0 = adj ? e0 : -1e9f;
        float e1 = si.y + dj.y; e1 = fmaxf(e1, 0.2f * e1); e1 = adj ? e1 : -1e9f;
        float e2 = si.z + dj.z; e2 = fmaxf(e2, 0.2f * e2); e2 = adj ? e2 : -1e9f;
        float e3 = si.w + dj.w; e3 = fmaxf(e3, 0.2f * e3); e3 = adj ? e3 : -1e9f;
        cand[it][0] = e0; cand[it][1] = e1; cand[it][2] = e2; cand[it][3] = e3;
        mv0 = fmaxf(mv0, e0); mv1 = fmaxf(mv1, e1);
        mv2 = fmaxf(mv2, e2); mv3 = fmaxf(mv3, e3);
    }
    __shared__ float4 red[256];
    red[t] = make_float4(mv0, mv1, mv2, mv3);
    __syncthreads();
    for (int off = 128; off; off >>= 1) {
        if (t < off) {
            float4 a = red[t], c = red[t + off];
            red[t] = make_float4(fmaxf(a.x, c.x), fmaxf(a.y, c.y),
                                 fmaxf(a.z, c.z), fmaxf(a.w, c.w));
        }
        __syncthreads();
    }
    float4 m = red[0];
    __syncthreads();
    float s0 = 0.f, s1 = 0.f, s2 = 0.f, s3 = 0.f;
    for (int it = 0; it < nIter; ++it) {
        s0 += __expf(cand[it][0] - m.x);
        s1 += __expf(cand[it][1] - m.y);
        s2 += __expf(cand[it][2] - m.z);
        s3 += __expf(cand[it][3] - m.w);
    }
    red[t] = make_float4(s0, s1, s2, s3);
    __syncthreads();
    for (int off = 128; off; off >>= 1) {
        if (t < off) {
            float4 a = red[t], c = red[t + off];
            red[t] = make_float4(a.x + c.x, a.y + c.y, a.z + c.z, a.w + c.w);
        }
        __syncthreads();
    }
    if (t == 0) { m4[bi] = m; s4[bi] = red[0]; }
}

// GAT aggregation as MFMA GEMM. Block = (b, 32 i-rows); wave = head.
__global__ __launch_bounds__(256) void k_gatagg_mm(
    const bf16* __restrict__ hgT,
    const unsigned long long* __restrict__ adjm,
    const float4* __restrict__ srcv, const float4* __restrict__ m4,
    const float4* __restrict__ s4, const float4* __restrict__ dstv,
    const float* __restrict__ res, int resBatchStride,
    bf16* __restrict__ outb, int nN)
{
    __shared__ float dstT[4][1024];
    __shared__ unsigned int adjW[32][33];
    const int t = threadIdx.x;
    const int nblk = nN >> 5;
    const int b = blockIdx.x / nblk;
    const int i0 = (blockIdx.x - b * nblk) << 5;
    const int nC = nN >> 6;
    for (int j = t; j < nN; j += 256) {
        float4 dj = dstv[(long)b * nN + j];
        dstT[0][j] = dj.x; dstT[1][j] = dj.y; dstT[2][j] = dj.z; dstT[3][j] = dj.w;
    }
    for (int idx = t; idx < 32 * nC; idx += 256) {
        int r = idx / nC, c = idx - r * nC;
        unsigned long long v = adjm[((long)b * nN + i0 + r) * nC + c];
        adjW[r][c * 2] = (unsigned)v;
        adjW[r][c * 2 + 1] = (unsigned)(v >> 32);
    }
    __syncthreads();
    const int h = t >> 6, lane = t & 63, lr = lane & 15, kq = lane >> 4;
    float s_r[2], m_r[2];
    #pragma unroll
    for (int mt = 0; mt < 2; ++mt) {
        long idx = (long)b * nN + i0 + mt * 16 + lr;
        s_r[mt] = ((const float*)(srcv + idx))[h];
        m_r[mt] = ((const float*)(m4 + idx))[h];
    }
    f32x4 acc[2][4] = {};
    const bf16* hb = hgT + ((long)b * 256 + h * 64) * nN;
    for (int j0 = 0; j0 < nN; j0 += 32) {
        bf16x8 bfr[4];
        #pragma unroll
        for (int nt = 0; nt < 4; ++nt)
            bfr[nt] = *(const bf16x8*)(hb + (long)(nt * 16 + lr) * nN + j0 + kq * 8);
        #pragma unroll
        for (int mt = 0; mt < 2; ++mt) {
            unsigned byte = (adjW[mt * 16 + lr][j0 >> 5] >> (kq * 8)) & 0xffu;
            bf16x8 af;
            #pragma unroll
            for (int jj = 0; jj < 8; ++jj) {
                float e = s_r[mt] + dstT[h][j0 + kq * 8 + jj];
                e = fmaxf(e, 0.2f * e);
                e = (byte & (1u << jj)) ? e : -1e9f;
                af[jj] = f2bf(__expf(e - m_r[mt]));
            }
            #pragma unroll
            for (int nt = 0; nt < 4; ++nt)
                acc[mt][nt] = __builtin_amdgcn_mfma_f32_16x16x32_bf16(af, bfr[nt], acc[mt][nt], 0, 0, 0);
        }
    }
    #pragma unroll
    for (int mt = 0; mt < 2; ++mt) {
        #pragma unroll
        for (int ii = 0; ii < 4; ++ii) {
            int i = i0 + mt * 16 + kq * 4 + ii;
            long bi = (long)b * nN + i;
            float rs = 1.f / fmaxf(((const float*)(s4 + bi))[h], 1e-30f);
            #pragma unroll
            for (int nt = 0; nt < 4; ++nt) {
                int col = h * 64 + nt * 16 + lr;
                float a = acc[mt][nt][ii] * rs;
                float e = a > 0.f ? a : expm1f(a);
                float v = 0.5f * e + 0.5f * res[(long)b * resBatchStride + (long)i * 256 + col];
                outb[bi * 256 + col] = f2bf(v);
            }
        }
    }
}

// ---------------------------------------------------------------------------
extern "C" void kernel_launch(void* const* d_in, const int* in_sizes, int n_in,
                              void* d_out, int out_size, void* d_ws, size_t ws_size,
                              hipStream_t stream)
{
    (void)in_sizes; (void)n_in; (void)out_size; (void)ws_size;
    const float* tracks = (const float*)d_in[0];
    const float* dets   = (const float*)d_in[1];
    const int*  tmarks = (const int*)d_in[2];
    const int*  dmarks = (const int*)d_in[3];
    const float* W1   = (const float*)d_in[4];
    const float* b1   = (const float*)d_in[5];
    const float* W2   = (const float*)d_in[6];
    const float* b2   = (const float*)d_in[7];
    const float* Wqkv = (const float*)d_in[8];
    const float* Wo   = (const float*)d_in[9];
    const float* eff1 = (const float*)d_in[10];
    const float* eff2 = (const float*)d_in[11];
    const float* gatW = (const float*)d_in[12];
    const float* gatA = (const float*)d_in[13];
    const float* dgatW = (const float*)d_in[14];
    const float* dgatA = (const float*)d_in[15];
    const float* clsWq = (const float*)d_in[16];
    const float* clsWk = (const float*)d_in[17];
    float* out = (float*)d_out;

    char* wsb = (char*)d_ws;
    size_t off = 0;
    auto take = [&](size_t bytes) -> char* {
        char* p = wsb + off;
        off += (bytes + 255) & ~(size_t)255;
        return p;
    };
    char* R_emb  = take(37748736);   // emb_b; later x20(+0), h2_b(+8388608)
    char* R_r0   = take(8388608);    // emb_r0_f
    char* R_hln  = take(33554432);   // hln; later f1_b
    char* R_v    = take(33554432);   // v_b; later xq_b(+0), xk_b(+8388608)
    char* R_gat  = take(25165824);   // hgT(+0), xga_b(+8388608), xgb_b(+16777216)
    char* R_q    = take(4194304);    // q_b
    char* R_o0   = take(4194304);    // o0_b
    char* R_f0f  = take(16777216);   // feat0_f
    char* R_f0b  = take(8388608);    // feat0_b
    char* R_demb = take(4194304);    // demb_b
    float4* nodes = (float4*)take(262144);
    float4* src4  = (float4*)take(262144);
    float4* dst4  = (float4*)take(262144);
    float4* m4    = (float4*)take(262144);
    float4* s4    = (float4*)take(262144);
    unsigned long long* adjm_main = (unsigned long long*)take(2097152);
    unsigned long long* adjm_det  = (unsigned long long*)take(524288);
    bf16* wbuf = (bf16*)take(2752512);   // transposed bf16 weights

    bf16*  emb_b    = (bf16*)R_emb;
    float* emb_r0_f = (float*)R_r0;
    bf16*  hln      = (bf16*)R_hln;
    bf16*  v_b      = (bf16*)R_v;
    bf16*  k_b      = (bf16*)d_out;         // scratch in d_out; dead before logits
    bf16*  q_b      = (bf16*)R_q;
    bf16*  o0_b     = (bf16*)R_o0;
    float* x20      = (float*)R_emb;
    bf16*  h2_b     = (bf16*)(R_emb + 8388608);
    bf16*  f1_b     = (bf16*)R_hln;
    float* feat0_f  = (float*)R_f0f;
    bf16*  feat0_b  = (bf16*)R_f0b;
    bf16*  demb_b   = (bf16*)R_demb;
    bf16*  hgT      = (bf16*)R_gat;
    bf16*  xga_b    = (bf16*)(R_gat + 8388608);
    bf16*  xgb_b    = (bf16*)(R_gat + 16777216);
    bf16*  xq_b     = (bf16*)R_v;
    bf16*  xk_b     = (bf16*)(R_v + 8388608);

    // transposed-weight table (dst offsets in bf16 elems; tile prefix sums)
    bf16* W2T    = wbuf + 0;
    bf16* WqkvT  = wbuf + 65536;
    bf16* WoT    = wbuf + 262144;
    bf16* eff1T  = wbuf + 327680;
    bf16* eff2T  = wbuf + 589824;
    bf16* gatW0T = wbuf + 851968;
    bf16* gatW1T = wbuf + 917504;
    bf16* dgatW0T= wbuf + 983040;
    bf16* dgatW1T= wbuf + 1048576;
    bf16* clsWq0T= wbuf + 1114112;
    bf16* clsWk0T= wbuf + 1179648;
    bf16* clsWq1T= wbuf + 1245184;
    bf16* clsWk1T= wbuf + 1310720;
    PrepTab tab;
    tab.e[0]  = { W2,             0,       256,  256,  0    };
    tab.e[1]  = { Wqkv,           65536,   256,  768,  64   };
    tab.e[2]  = { Wo,             262144,  256,  256,  256  };
    tab.e[3]  = { eff1,           327680,  256,  1024, 320  };
    tab.e[4]  = { eff2,           589824,  1024, 256,  576  };
    tab.e[5]  = { gatW,           851968,  256,  256,  832  };
    tab.e[6]  = { gatW + 65536,   917504,  256,  256,  896  };
    tab.e[7]  = { dgatW,          983040,  256,  256,  960  };
    tab.e[8]  = { dgatW + 65536,  1048576, 256,  256,  1024 };
    tab.e[9]  = { clsWq,          1114112, 256,  256,  1088 };
    tab.e[10] = { clsWk,          1179648, 256,  256,  1152 };
    tab.e[11] = { clsWq + 65536,  1245184, 256,  256,  1216 };
    tab.e[12] = { clsWk + 65536,  1310720, 256,  256,  1280 };

    // prep + graph + embeddings
    k_prep<<<1344, 256, 0, stream>>>(tab, wbuf);
    k_nodes<<<64, 256, 0, stream>>>(tracks, dets, tmarks, dmarks, nodes);
    k_adjmask<<<16384, 256, 0, stream>>>(nodes, adjm_main, 1024, 10, 0);
    k_adjmask<<<8192, 256, 0, stream>>>(nodes, adjm_det, 512, 9, 512);
    k_featgemm<<<1152, 256, 0, stream>>>(tracks, dets, W1, b1, W2T, b2,
        emb_b, emb_r0_f, feat0_f, feat0_b, demb_b);

    // encoder (only r=0 row needed downstream of attention)
    k_ln_bf16<<<16384, 256, 0, stream>>>(emb_b, hln);
    k_gemm_bf16<<<dim3(4, 1024, 1), 256, 0, stream>>>(hln, 256, WqkvT + 256 * 256, 256, k_b, 256, 256, 0);
    k_gemm_bf16<<<dim3(4, 1024, 1), 256, 0, stream>>>(hln, 256, WqkvT + 512 * 256, 256, v_b, 256, 256, 0);
    k_gemm_bf16<<<dim3(4, 128, 1), 256, 0, stream>>>(hln, 2048, WqkvT, 256, q_b, 256, 256, 0);
    k_attn<<<8192, 256, 0, stream>>>(q_b, k_b, v_b, o0_b);
    k_gemm_addres<<<dim3(4, 128, 1), 256, 0, stream>>>(o0_b, 256, WoT, 256, emb_r0_f, 256, x20, 256, 256);
    k_ln_f32<<<2048, 256, 0, stream>>>(x20, h2_b);
    k_gemm_bf16<<<dim3(16, 128, 1), 256, 0, stream>>>(h2_b, 256, eff1T, 256, f1_b, 1024, 256, 1);
    k_gemm_pred<<<dim3(4, 128, 1), 256, 0, stream>>>(f1_b, 1024, eff2T, 1024, emb_r0_f, x20, feat0_f, feat0_b, 1024);

    // main GAT layer 1
    k_gemm_T<<<dim3(256, 4, 1), 256, 0, stream>>>(gatW0T, feat0_b, hgT, 1024, 10);
    k_srcdst_T<<<256, 256, 0, stream>>>(hgT, gatA, (float*)src4, (float*)dst4, 1024, 10);
    k_gatms<<<16384, 256, 0, stream>>>(nodes, src4, dst4, m4, s4, 1024, 0);
    k_gatagg_mm<<<512, 256, 0, stream>>>(hgT, adjm_main, src4, m4, s4, dst4,
        feat0_f, 262144, xga_b, 1024);
    // main GAT layer 2
    k_gemm_T<<<dim3(256, 4, 1), 256, 0, stream>>>(gatW1T, xga_b, hgT, 1024, 10);
    k_srcdst_T<<<256, 256, 0, stream>>>(hgT, gatA + 512, (float*)src4, (float*)dst4, 1024, 10);
    k_gatms<<<16384, 256, 0, stream>>>(nodes, src4, dst4, m4, s4, 1024, 0);
    k_gatagg_mm<<<512, 256, 0, stream>>>(hgT, adjm_main, src4, m4, s4, dst4,
        feat0_f, 262144, xgb_b, 1024);
    // main scores + asso
    k_gemm_bf16<<<dim3(4, 256, 1), 256, 0, stream>>>(xgb_b, 256, clsWq0T, 256, xq_b, 256, 256, 0);
    k_gemm_bf16<<<dim3(4, 256, 1), 256, 0, stream>>>(xgb_b, 256, clsWk0T, 256, xk_b, 256, 256, 0);
    k_gemm_logits<<<dim3(16, 16, 16), 256, 0, stream>>>(xq_b, 262144L, xk_b, 262144L, 256,
        out, 1024, 1048576L, nodes, 0, out + 20971520L, 1);

    // det branch
    k_gemm_T<<<dim3(128, 4, 1), 256, 0, stream>>>(dgatW0T, demb_b, hgT, 512, 9);
    k_srcdst_T<<<128, 256, 0, stream>>>(hgT, dgatA, (float*)src4, (float*)dst4, 512, 9);
    k_gatms<<<8192, 256, 0, stream>>>(nodes, src4, dst4, m4, s4, 512, 512);
    k_gatagg_mm<<<256, 256, 0, stream>>>(hgT, adjm_det, src4, m4, s4, dst4,
        feat0_f + 131072, 262144, xga_b, 512);
    k_gemm_T<<<dim3(128, 4, 1), 256, 0, stream>>>(dgatW1T, xga_b, hgT, 512, 9);
    k_srcdst_T<<<128, 256, 0, stream>>>(hgT, dgatA + 512, (float*)src4, (float*)dst4, 512, 9);
    k_gatms<<<8192, 256, 0, stream>>>(nodes, src4, dst4, m4, s4, 512, 512);
    k_gatagg_mm<<<256, 256, 0, stream>>>(hgT, adjm_det, src4, m4, s4, dst4,
        feat0_f + 131072, 262144, xgb_b, 512);
    k_gemm_bf16<<<dim3(4, 128, 1), 256, 0, stream>>>(xgb_b, 256, clsWq1T, 256, xq_b, 256, 256, 0);
    k_gemm_bf16<<<dim3(4, 128, 1), 256, 0, stream>>>(xgb_b, 256, clsWk1T, 256, xk_b, 256, 256, 0);
    k_gemm_logits<<<dim3(8, 8, 16), 256, 0, stream>>>(xq_b, 131072L, xk_b, 131072L, 256,
        out + 16777216L, 512, 262144L, nodes, 512, (float*)nullptr, 2);
}

// Round 6
// 600.983 us; speedup vs baseline: 3.7989x; 1.1794x over previous
//
#include <hip/hip_runtime.h>
#include <math.h>

// ScatterNet_21706764714521 — round 6: k_gatms eliminated (upper-bound max +
// in-MFMA softmax denominator), K/V GEMM fused. fp32 I/O, bf16 MFMA inside.

typedef __bf16 bf16;
typedef __bf16 bf16x8 __attribute__((ext_vector_type(8)));
typedef __bf16 bf16x4 __attribute__((ext_vector_type(4)));
typedef float f32x4 __attribute__((ext_vector_type(4)));

__device__ __forceinline__ float bf2f(bf16 x) { return (float)x; }
__device__ __forceinline__ bf16 f2bf(float x) { return (bf16)x; }

// node record: (x, y, invalid?1e9:0, 0). adjacency = dist<2 && both valid.
__device__ __forceinline__ bool node_adj(float4 a, float4 c) {
    float dx = a.x - c.x, dy = a.y - c.y;
    return (sqrtf(dx * dx + dy * dy) + a.z + c.z) < 2.0f;
}

// ---------------------------------------------------------------------------
// Weight prep: transpose+convert fp32 [R][C] -> bf16 [C][R], 32x32 tiles.
// ---------------------------------------------------------------------------
struct PrepEnt { const float* src; long dofs; int R; int C; int tstart; };
struct PrepTab { PrepEnt e[13]; };

__global__ __launch_bounds__(256) void k_prep(PrepTab tab, bf16* __restrict__ dst)
{
    __shared__ float tile[32][33];
    const int tid = blockIdx.x;
    int k = 0;
    #pragma unroll
    for (int q = 1; q < 13; ++q) if (tid >= tab.e[q].tstart) k = q;
    PrepEnt E = tab.e[k];
    const int local = tid - E.tstart;
    const int cT = E.C >> 5;
    const int tr = local / cT, tc = local - tr * cT;
    const int r0 = tr << 5, c0 = tc << 5;
    const int t = threadIdx.x;
    {
        int r = t >> 3, cq = (t & 7) * 4;
        *(float4*)&tile[r][cq] = *(const float4*)(E.src + (long)(r0 + r) * E.C + c0 + cq);
    }
    __syncthreads();
    {
        int c = t >> 3, rq = (t & 7) * 4;
        bf16x4 o;
        o[0] = f2bf(tile[rq + 0][c]); o[1] = f2bf(tile[rq + 1][c]);
        o[2] = f2bf(tile[rq + 2][c]); o[3] = f2bf(tile[rq + 3][c]);
        *(bf16x4*)(dst + E.dofs + (long)(c0 + c) * E.R + r0 + rq) = o;
    }
}

// ---------------------------------------------------------------------------
// MFMA GEMM core: C(64x64/block) = A(MxK) @ BT(NxK)^T, bf16 in, fp32 acc.
// D mapping: row = m0 + wv*16 + kq*4 + i, col = n0 + nt*16 + lr.
// ---------------------------------------------------------------------------
__device__ __forceinline__ void gemm_bt(const bf16* __restrict__ A, int lda,
                                        const bf16* __restrict__ BT, int ldb,
                                        int K, f32x4 acc[4])
{
    __shared__ bf16 As[64][40];
    __shared__ bf16 Bs[64][40];
    const int t = threadIdx.x;
    const int m0 = blockIdx.y * 64;
    const int n0 = blockIdx.x * 64;
    const int lane = t & 63, wv = t >> 6, lr = lane & 15, kq = lane >> 4;
    const int arow = t >> 2, acol = (t & 3) * 8;
    for (int k0 = 0; k0 < K; k0 += 32) {
        __syncthreads();
        *(uint4*)&As[arow][acol] = *(const uint4*)(A + (long)(m0 + arow) * lda + k0 + acol);
        *(uint4*)&Bs[arow][acol] = *(const uint4*)(BT + (long)(n0 + arow) * ldb + k0 + acol);
        __syncthreads();
        bf16x8 af = *(const bf16x8*)&As[wv * 16 + lr][kq * 8];
        #pragma unroll
        for (int nt = 0; nt < 4; ++nt) {
            bf16x8 bfr = *(const bf16x8*)&Bs[nt * 16 + lr][kq * 8];
            acc[nt] = __builtin_amdgcn_mfma_f32_16x16x32_bf16(af, bfr, acc[nt], 0, 0, 0);
        }
    }
}

__global__ __launch_bounds__(256) void k_gemm_bf16(
    const bf16* __restrict__ A, int lda,
    const bf16* __restrict__ BT, int ldb,
    bf16* __restrict__ out, int ldo, int K, int relu)
{
    f32x4 acc[4] = {};
    gemm_bt(A, lda, BT, ldb, K, acc);
    const int lane = threadIdx.x & 63, wv = threadIdx.x >> 6;
    const int lr = lane & 15, kq = lane >> 4;
    const int m0 = blockIdx.y * 64, n0 = blockIdx.x * 64;
    #pragma unroll
    for (int nt = 0; nt < 4; ++nt) {
        int col = n0 + nt * 16 + lr;
        #pragma unroll
        for (int i = 0; i < 4; ++i) {
            int row = m0 + wv * 16 + kq * 4 + i;
            float v = acc[nt][i];
            if (relu) v = fmaxf(v, 0.f);
            out[(long)row * ldo + col] = f2bf(v);
        }
    }
}

// out = res1 + acc (fp32 out)
__global__ __launch_bounds__(256) void k_gemm_addres(
    const bf16* __restrict__ A, int lda,
    const bf16* __restrict__ BT, int ldb,
    const float* __restrict__ res1, int ldr1,
    float* __restrict__ outf, int ldo, int K)
{
    f32x4 acc[4] = {};
    gemm_bt(A, lda, BT, ldb, K, acc);
    const int lane = threadIdx.x & 63, wv = threadIdx.x >> 6;
    const int lr = lane & 15, kq = lane >> 4;
    const int m0 = blockIdx.y * 64, n0 = blockIdx.x * 64;
    #pragma unroll
    for (int nt = 0; nt < 4; ++nt) {
        int col = n0 + nt * 16 + lr;
        #pragma unroll
        for (int i = 0; i < 4; ++i) {
            int row = m0 + wv * 16 + kq * 4 + i;
            outf[(long)row * ldo + col] = res1[(long)row * ldr1 + col] + acc[nt][i];
        }
    }
}

// predicted = tr_emb0 + 0.9*(x2_0 + ff2_out); scattered to feat0[b*1024+m]
__global__ __launch_bounds__(256) void k_gemm_pred(
    const bf16* __restrict__ A, int lda,
    const bf16* __restrict__ BT, int ldb,
    const float* __restrict__ res1, const float* __restrict__ res2,
    float* __restrict__ outf, bf16* __restrict__ outb, int K)
{
    f32x4 acc[4] = {};
    gemm_bt(A, lda, BT, ldb, K, acc);
    const int lane = threadIdx.x & 63, wv = threadIdx.x >> 6;
    const int lr = lane & 15, kq = lane >> 4;
    const int m0 = blockIdx.y * 64, n0 = blockIdx.x * 64;
    #pragma unroll
    for (int nt = 0; nt < 4; ++nt) {
        int col = n0 + nt * 16 + lr;
        #pragma unroll
        for (int i = 0; i < 4; ++i) {
            int row = m0 + wv * 16 + kq * 4 + i;     // b*512 + m
            float v = res1[(long)row * 256 + col]
                    + 0.9f * (res2[(long)row * 256 + col] + acc[nt][i]);
            long drow = (long)row + ((row >> 9) << 9);   // b*1024 + m
            long o = drow * 256 + col;
            outf[o] = v;
            outb[o] = f2bf(v);
        }
    }
}

// scores = sigmoid(acc/16) * adj (fp32 out); optional asso copy / zero diag
__global__ __launch_bounds__(256) void k_gemm_logits(
    const bf16* __restrict__ A, long sAz,
    const bf16* __restrict__ Bm, long sBz, int K,
    float* __restrict__ out, int ldo, long sOz,
    const float4* __restrict__ nodes, int nodeOfs,
    float* __restrict__ asso, int flags)
{
    f32x4 acc[4] = {};
    const int z = blockIdx.z;
    gemm_bt(A + z * sAz, 256, Bm + z * sBz, 256, K, acc);
    const int lane = threadIdx.x & 63, wv = threadIdx.x >> 6;
    const int lr = lane & 15, kq = lane >> 4;
    const int m0 = blockIdx.y * 64, n0 = blockIdx.x * 64;
    const float4* nb = nodes + z * 1024 + nodeOfs;
    float4 nrow[4], ncol[4];
    #pragma unroll
    for (int i = 0; i < 4; ++i) nrow[i] = nb[m0 + wv * 16 + kq * 4 + i];
    #pragma unroll
    for (int nt = 0; nt < 4; ++nt) ncol[nt] = nb[n0 + nt * 16 + lr];
    float* ob = out + z * sOz;
    #pragma unroll
    for (int nt = 0; nt < 4; ++nt) {
        int col = n0 + nt * 16 + lr;
        #pragma unroll
        for (int i = 0; i < 4; ++i) {
            int row = m0 + wv * 16 + kq * 4 + i;
            bool adj = node_adj(nrow[i], ncol[nt]);
            if ((flags & 2) && row == col) adj = false;
            float v = 0.f;
            if (adj) v = 1.f / (1.f + __expf(-acc[nt][i] * 0.0625f));
            ob[(long)row * ldo + col] = v;
            if ((flags & 1) && row < 512 && col >= 512)
                asso[(long)z * 262144 + (long)row * 512 + (col - 512)] = v;
        }
    }
}

// GAT projection, transposed output: hgT[b][d][j] = (X @ W)[b*nN+j][d]
__global__ __launch_bounds__(256) void k_gemm_T(
    const bf16* __restrict__ WT, const bf16* __restrict__ X,
    bf16* __restrict__ hgT, int nN, int nLog)
{
    f32x4 acc[4] = {};
    gemm_bt(WT, 256, X, 256, 256, acc);
    const int lane = threadIdx.x & 63, wv = threadIdx.x >> 6;
    const int lr = lane & 15, kq = lane >> 4;
    const int d0 = blockIdx.y * 64, n0 = blockIdx.x * 64;
    #pragma unroll
    for (int nt = 0; nt < 4; ++nt) {
        int node = n0 + nt * 16 + lr;
        int b = node >> nLog;
        int j = node & (nN - 1);
        #pragma unroll
        for (int i = 0; i < 4; ++i) {
            int d = d0 + wv * 16 + kq * 4 + i;
            hgT[((long)(b * 256 + d) << nLog) + j] = f2bf(acc[nt][i]);
        }
    }
}

// ---------------------------------------------------------------------------
// fused feat MLP, wide-N: block = 64 rows x all 256 cols.
// ---------------------------------------------------------------------------
__global__ __launch_bounds__(256) void k_featgemm(
    const float* __restrict__ tracks, const float* __restrict__ dets,
    const float* __restrict__ W1, const float* __restrict__ b1,
    const bf16* __restrict__ W2T, const float* __restrict__ b2,
    bf16* __restrict__ emb_b, float* __restrict__ emb_r0_f,
    float* __restrict__ feat0_f, bf16* __restrict__ feat0_b,
    bf16* __restrict__ demb_b)
{
    __shared__ float xr[64][4];
    __shared__ float w1s[4][256];
    __shared__ float b1s[256];
    __shared__ bf16 As[64][40];
    __shared__ bf16 Bs[256][40];
    const int t = threadIdx.x;
    const int m0 = blockIdx.x * 64;
    if (t < 64) {
        int gr = m0 + t;
        const float* sp = (gr < 65536) ? (tracks + (long)gr * 4)
                                       : (dets + (long)(gr - 65536) * 4);
        *(float4*)&xr[t][0] = *(const float4*)sp;
    }
    w1s[0][t] = W1[t];       w1s[1][t] = W1[256 + t];
    w1s[2][t] = W1[512 + t]; w1s[3][t] = W1[768 + t];
    b1s[t] = b1[t];
    const int arow = t >> 2, acol = (t & 3) * 8;
    const int lane = t & 63, wv = t >> 6, lr = lane & 15, kq = lane >> 4;
    f32x4 acc[16] = {};
    __syncthreads();
    for (int k0 = 0; k0 < 256; k0 += 32) {
        __syncthreads();
        #pragma unroll
        for (int j = 0; j < 8; ++j) {
            int c = k0 + acol + j;
            float v = fmaf(xr[arow][0], w1s[0][c],
                      fmaf(xr[arow][1], w1s[1][c],
                      fmaf(xr[arow][2], w1s[2][c],
                      fmaf(xr[arow][3], w1s[3][c], b1s[c]))));
            v = v > 0.f ? v : (__expf(v) - 1.f);
            As[arow][acol + j] = f2bf(v);
        }
        #pragma unroll
        for (int rr = 0; rr < 4; ++rr) {
            int n = rr * 64 + (t >> 2);
            *(uint4*)&Bs[n][acol] = *(const uint4*)(W2T + (long)n * 256 + k0 + acol);
        }
        __syncthreads();
        bf16x8 af = *(const bf16x8*)&As[wv * 16 + lr][kq * 8];
        #pragma unroll
        for (int nt = 0; nt < 16; ++nt) {
            bf16x8 bfr = *(const bf16x8*)&Bs[nt * 16 + lr][kq * 8];
            acc[nt] = __builtin_amdgcn_mfma_f32_16x16x32_bf16(af, bfr, acc[nt], 0, 0, 0);
        }
    }
    #pragma unroll
    for (int nt = 0; nt < 16; ++nt) {
        int col = nt * 16 + lr;
        float bv = b2[col];
        #pragma unroll
        for (int i = 0; i < 4; ++i) {
            int gr = m0 + wv * 16 + kq * 4 + i;
            float v = acc[nt][i] + bv;
            emb_b[(long)gr * 256 + col] = f2bf(v);
            if (gr < 65536) {
                if ((gr & 7) == 0) emb_r0_f[(long)(gr >> 3) * 256 + col] = v;
            } else {
                int dr = gr - 65536;
                long drow = ((long)(dr >> 9) << 10) + 512 + (dr & 511);
                feat0_f[drow * 256 + col] = v;
                feat0_b[drow * 256 + col] = f2bf(v);
                demb_b[(long)dr * 256 + col] = f2bf(v);
            }
        }
    }
}

// adjacency bitmask rows via ballot
__global__ __launch_bounds__(256) void k_adjmask(
    const float4* __restrict__ nodes, unsigned long long* __restrict__ adjm,
    int nN, int nLog, int nodeOfs)
{
    const int bi = blockIdx.x;
    const int b = bi >> nLog;
    const int i = bi & (nN - 1);
    const float4* nb = nodes + b * 1024 + nodeOfs;
    const float4 ni = nb[i];
    const int t = threadIdx.x;
    const int w = t >> 6, lane = t & 63;
    const int nC = nN >> 6;
    for (int it = 0; it * 256 < nN; ++it) {
        int j = it * 256 + t;
        bool adj = node_adj(ni, nb[j]);
        unsigned long long mask = __ballot(adj);
        if (lane == 0) adjm[(long)bi * nC + it * 4 + w] = mask;
    }
}

// LayerNorm wave-per-row (4 rows/block)
__global__ __launch_bounds__(256) void k_ln_bf16(const bf16* __restrict__ x, bf16* __restrict__ out)
{
    const int w = threadIdx.x >> 6, l = threadIdx.x & 63;
    const long row = (long)blockIdx.x * 4 + w;
    bf16x4 xv = *(const bf16x4*)(x + row * 256 + l * 4);
    float v0 = bf2f(xv[0]), v1 = bf2f(xv[1]), v2 = bf2f(xv[2]), v3 = bf2f(xv[3]);
    float s = v0 + v1 + v2 + v3;
    #pragma unroll
    for (int o = 32; o; o >>= 1) s += __shfl_xor(s, o, 64);
    float mean = s * (1.f / 256.f);
    float d0 = v0 - mean, d1 = v1 - mean, d2 = v2 - mean, d3 = v3 - mean;
    float q = d0 * d0 + d1 * d1 + d2 * d2 + d3 * d3;
    #pragma unroll
    for (int o = 32; o; o >>= 1) q += __shfl_xor(q, o, 64);
    float rstd = rsqrtf(q * (1.f / 256.f) + 1e-5f);
    bf16x4 ov;
    ov[0] = f2bf(d0 * rstd); ov[1] = f2bf(d1 * rstd);
    ov[2] = f2bf(d2 * rstd); ov[3] = f2bf(d3 * rstd);
    *(bf16x4*)(out + row * 256 + l * 4) = ov;
}

__global__ __launch_bounds__(256) void k_ln_f32(const float* __restrict__ x, bf16* __restrict__ out)
{
    const int w = threadIdx.x >> 6, l = threadIdx.x & 63;
    const long row = (long)blockIdx.x * 4 + w;
    float4 xv = *(const float4*)(x + row * 256 + l * 4);
    float s = xv.x + xv.y + xv.z + xv.w;
    #pragma unroll
    for (int o = 32; o; o >>= 1) s += __shfl_xor(s, o, 64);
    float mean = s * (1.f / 256.f);
    float d0 = xv.x - mean, d1 = xv.y - mean, d2 = xv.z - mean, d3 = xv.w - mean;
    float q = d0 * d0 + d1 * d1 + d2 * d2 + d3 * d3;
    #pragma unroll
    for (int o = 32; o; o >>= 1) q += __shfl_xor(q, o, 64);
    float rstd = rsqrtf(q * (1.f / 256.f) + 1e-5f);
    bf16x4 ov;
    ov[0] = f2bf(d0 * rstd); ov[1] = f2bf(d1 * rstd);
    ov[2] = f2bf(d2 * rstd); ov[3] = f2bf(d3 * rstd);
    *(bf16x4*)(out + row * 256 + l * 4) = ov;
}

// encoder attention, r=0 row only. kv layout: [row][512] (K cols 0..255, V 256..511)
__global__ __launch_bounds__(256) void k_attn(
    const bf16* __restrict__ q, const bf16* __restrict__ kv,
    bf16* __restrict__ o0)
{
    const long t = blockIdx.x;
    const int h = threadIdx.x >> 6;
    const int lane = threadIdx.x & 63;
    const int s = lane >> 3;
    const int dg = lane & 7;
    const bf16* qp = q + t * 256 + h * 64 + dg * 8;
    const bf16* kp = kv + (t * 8 + s) * 512 + h * 64 + dg * 8;
    float p = 0.f;
    #pragma unroll
    for (int e = 0; e < 8; ++e) p += bf2f(qp[e]) * bf2f(kp[e]);
    p += __shfl_xor(p, 1, 64);
    p += __shfl_xor(p, 2, 64);
    p += __shfl_xor(p, 4, 64);
    float sc = p * 0.125f;
    float w[8];
    float mx = -1e30f;
    #pragma unroll
    for (int s2 = 0; s2 < 8; ++s2) { w[s2] = __shfl(sc, s2 * 8, 64); mx = fmaxf(mx, w[s2]); }
    float sum = 0.f;
    #pragma unroll
    for (int s2 = 0; s2 < 8; ++s2) { w[s2] = __expf(w[s2] - mx); sum += w[s2]; }
    float rs = 1.f / sum;
    float acc = 0.f;
    const bf16* vp = kv + (t * 8) * 512 + 256 + h * 64 + lane;
    #pragma unroll
    for (int s2 = 0; s2 < 8; ++s2) acc += w[s2] * bf2f(vp[(long)s2 * 512]);
    o0[t * 256 + h * 64 + lane] = f2bf(acc * rs);
}

__global__ __launch_bounds__(256) void k_nodes(
    const float* __restrict__ tracks, const float* __restrict__ dets,
    const int* __restrict__ tm, const int* __restrict__ dm,
    float4* __restrict__ nodes)
{
    int idx = blockIdx.x * 256 + threadIdx.x;
    int b = idx >> 10;
    int i = idx & 1023;
    float x, y;
    int valid;
    if (i < 512) {
        long o = (long)(b * 512 + i) * 32;
        x = tracks[o]; y = tracks[o + 1];
        valid = (i < tm[b]) ? 1 : 0;
    } else {
        int n = i - 512;
        long o = (long)(b * 512 + n) * 4;
        x = dets[o]; y = dets[o + 1];
        valid = (n < dm[b]) ? 1 : 0;
    }
    nodes[idx] = make_float4(x, y, valid ? 0.f : 1e9f, 0.f);
}

// GAT src/dst dots from hgT; block = 64 nodes x 4 heads
__global__ __launch_bounds__(256) void k_srcdst_T(
    const bf16* __restrict__ hgT, const float* __restrict__ av,
    float* __restrict__ src, float* __restrict__ dst, int nN, int nLog)
{
    __shared__ float avs[512];
    const int t = threadIdx.x;
    avs[t] = av[t]; avs[256 + t] = av[256 + t];
    __syncthreads();
    const int jl = t & 63, h = t >> 6;
    const int n = blockIdx.x * 64 + jl;
    const int b = n >> nLog, j = n & (nN - 1);
    const bf16* base = hgT + (((long)b * 256 + h * 64) << nLog) + j;
    float p0 = 0.f, p1 = 0.f;
    #pragma unroll 8
    for (int dd = 0; dd < 64; ++dd) {
        float v = bf2f(base[(long)dd << nLog]);
        p0 += v * avs[h * 64 + dd];
        p1 += v * avs[256 + h * 64 + dd];
    }
    src[(long)n * 4 + h] = p0;
    dst[(long)n * 4 + h] = p1;
}

// per-batch per-head max of dst (upper bound for softmax max)
__global__ __launch_bounds__(256) void k_maxdst(
    const float4* __restrict__ dstv, float4* __restrict__ maxd, int nN)
{
    const int b = blockIdx.x;
    const int t = threadIdx.x;
    float4 mv = make_float4(-1e30f, -1e30f, -1e30f, -1e30f);
    for (int j = t; j < nN; j += 256) {
        float4 dj = dstv[(long)b * nN + j];
        mv.x = fmaxf(mv.x, dj.x); mv.y = fmaxf(mv.y, dj.y);
        mv.z = fmaxf(mv.z, dj.z); mv.w = fmaxf(mv.w, dj.w);
    }
    __shared__ float4 red[256];
    red[t] = mv;
    __syncthreads();
    for (int off = 128; off; off >>= 1) {
        if (t < off) {
            float4 a = red[t], c = red[t + off];
            red[t] = make_float4(fmaxf(a.x, c.x), fmaxf(a.y, c.y),
                                 fmaxf(a.z, c.z), fmaxf(a.w, c.w));
        }
        __syncthreads();
    }
    if (t == 0) maxd[b] = red[0];
}

// GAT aggregation as MFMA GEMM with fused softmax denominator.
// Block = (b, 32 i-rows); wave = head. m̂ = leaky(src_i + max_j dst_j) upper bound.
__global__ __launch_bounds__(256) void k_gatagg_mm(
    const bf16* __restrict__ hgT,
    const unsigned long long* __restrict__ adjm,
    const float4* __restrict__ srcv, const float4* __restrict__ maxd,
    const float4* __restrict__ dstv,
    const float* __restrict__ res, int resBatchStride,
    bf16* __restrict__ outb, int nN)
{
    __shared__ float dstT[4][1024];
    __shared__ unsigned int adjW[32][33];
    const int t = threadIdx.x;
    const int nblk = nN >> 5;
    const int b = blockIdx.x / nblk;
    const int i0 = (blockIdx.x - b * nblk) << 5;
    const int nC = nN >> 6;
    for (int j = t; j < nN; j += 256) {
        float4 dj = dstv[(long)b * nN + j];
        dstT[0][j] = dj.x; dstT[1][j] = dj.y; dstT[2][j] = dj.z; dstT[3][j] = dj.w;
    }
    for (int idx = t; idx < 32 * nC; idx += 256) {
        int r = idx / nC, c = idx - r * nC;
        unsigned long long v = adjm[((long)b * nN + i0 + r) * nC + c];
        adjW[r][c * 2] = (unsigned)v;
        adjW[r][c * 2 + 1] = (unsigned)(v >> 32);
    }
    __syncthreads();
    const int h = t >> 6, lane = t & 63, lr = lane & 15, kq = lane >> 4;
    const float mdh = ((const float*)(maxd + b))[h];
    float s_r[2], m_r[2], psum[2] = {0.f, 0.f};
    #pragma unroll
    for (int mt = 0; mt < 2; ++mt) {
        long idx = (long)b * nN + i0 + mt * 16 + lr;
        s_r[mt] = ((const float*)(srcv + idx))[h];
        float tmp = s_r[mt] + mdh;
        m_r[mt] = fmaxf(tmp, 0.2f * tmp);
    }
    f32x4 acc[2][4] = {};
    const bf16* hb = hgT + ((long)b * 256 + h * 64) * nN;
    for (int j0 = 0; j0 < nN; j0 += 32) {
        bf16x8 bfr[4];
        #pragma unroll
        for (int nt = 0; nt < 4; ++nt)
            bfr[nt] = *(const bf16x8*)(hb + (long)(nt * 16 + lr) * nN + j0 + kq * 8);
        #pragma unroll
        for (int mt = 0; mt < 2; ++mt) {
            unsigned byte = (adjW[mt * 16 + lr][j0 >> 5] >> (kq * 8)) & 0xffu;
            bf16x8 af;
            float ps = 0.f;
            #pragma unroll
            for (int jj = 0; jj < 8; ++jj) {
                float e = s_r[mt] + dstT[h][j0 + kq * 8 + jj];
                e = fmaxf(e, 0.2f * e);
                e = (byte & (1u << jj)) ? e : -1e9f;
                float p = __expf(e - m_r[mt]);
                af[jj] = f2bf(p);
                ps += p;
            }
            psum[mt] += ps;
            #pragma unroll
            for (int nt = 0; nt < 4; ++nt)
                acc[mt][nt] = __builtin_amdgcn_mfma_f32_16x16x32_bf16(af, bfr[nt], acc[mt][nt], 0, 0, 0);
        }
    }
    // row-sum across the 4 k-quadrant lanes: all lanes end with s for row (lane&15)
    float stot[2];
    #pragma unroll
    for (int mt = 0; mt < 2; ++mt) {
        float v = psum[mt];
        v += __shfl_xor(v, 16, 64);
        v += __shfl_xor(v, 32, 64);
        stot[mt] = v;
    }
    #pragma unroll
    for (int mt = 0; mt < 2; ++mt) {
        #pragma unroll
        for (int ii = 0; ii < 4; ++ii) {
            int i = i0 + mt * 16 + kq * 4 + ii;
            long bi = (long)b * nN + i;
            float sv = __shfl(stot[mt], kq * 4 + ii, 64);
            float rs = 1.f / fmaxf(sv, 1e-30f);
            #pragma unroll
            for (int nt = 0; nt < 4; ++nt) {
                int col = h * 64 + nt * 16 + lr;
                float a = acc[mt][nt][ii] * rs;
                float e = a > 0.f ? a : expm1f(a);
                float v = 0.5f * e + 0.5f * res[(long)b * resBatchStride + (long)i * 256 + col];
                outb[bi * 256 + col] = f2bf(v);
            }
        }
    }
}

// ---------------------------------------------------------------------------
extern "C" void kernel_launch(void* const* d_in, const int* in_sizes, int n_in,
                              void* d_out, int out_size, void* d_ws, size_t ws_size,
                              hipStream_t stream)
{
    (void)in_sizes; (void)n_in; (void)out_size; (void)ws_size;
    const float* tracks = (const float*)d_in[0];
    const float* dets   = (const float*)d_in[1];
    const int*  tmarks = (const int*)d_in[2];
    const int*  dmarks = (const int*)d_in[3];
    const float* W1   = (const float*)d_in[4];
    const float* b1   = (const float*)d_in[5];
    const float* W2   = (const float*)d_in[6];
    const float* b2   = (const float*)d_in[7];
    const float* Wqkv = (const float*)d_in[8];
    const float* Wo   = (const float*)d_in[9];
    const float* eff1 = (const float*)d_in[10];
    const float* eff2 = (const float*)d_in[11];
    const float* gatW = (const float*)d_in[12];
    const float* gatA = (const float*)d_in[13];
    const float* dgatW = (const float*)d_in[14];
    const float* dgatA = (const float*)d_in[15];
    const float* clsWq = (const float*)d_in[16];
    const float* clsWk = (const float*)d_in[17];
    float* out = (float*)d_out;

    char* wsb = (char*)d_ws;
    size_t off = 0;
    auto take = [&](size_t bytes) -> char* {
        char* p = wsb + off;
        off += (bytes + 255) & ~(size_t)255;
        return p;
    };
    char* R_emb  = take(37748736);   // emb_b; later x20(+0), h2_b(+8388608)
    char* R_r0   = take(8388608);    // emb_r0_f
    char* R_hln  = take(33554432);   // hln; later f1_b
    char* R_v    = take(33554432);   // xq_b(+0), xk_b(+8388608)
    char* R_gat  = take(25165824);   // hgT(+0), xga_b(+8388608), xgb_b(+16777216)
    char* R_q    = take(4194304);    // q_b
    char* R_o0   = take(4194304);    // o0_b
    char* R_f0f  = take(16777216);   // feat0_f
    char* R_f0b  = take(8388608);    // feat0_b
    char* R_demb = take(4194304);    // demb_b
    float4* nodes = (float4*)take(262144);
    float4* src4  = (float4*)take(262144);
    float4* dst4  = (float4*)take(262144);
    float4* maxd4 = (float4*)take(256);
    unsigned long long* adjm_main = (unsigned long long*)take(2097152);
    unsigned long long* adjm_det  = (unsigned long long*)take(524288);
    bf16* wbuf = (bf16*)take(2752512);   // transposed bf16 weights

    bf16*  emb_b    = (bf16*)R_emb;
    float* emb_r0_f = (float*)R_r0;
    bf16*  hln      = (bf16*)R_hln;
    bf16*  kv_b     = (bf16*)d_out;         // 67MB scratch in d_out (100MB); dead before logits
    bf16*  q_b      = (bf16*)R_q;
    bf16*  o0_b     = (bf16*)R_o0;
    float* x20      = (float*)R_emb;
    bf16*  h2_b     = (bf16*)(R_emb + 8388608);
    bf16*  f1_b     = (bf16*)R_hln;
    float* feat0_f  = (float*)R_f0f;
    bf16*  feat0_b  = (bf16*)R_f0b;
    bf16*  demb_b   = (bf16*)R_demb;
    bf16*  hgT      = (bf16*)R_gat;
    bf16*  xga_b    = (bf16*)(R_gat + 8388608);
    bf16*  xgb_b    = (bf16*)(R_gat + 16777216);
    bf16*  xq_b     = (bf16*)R_v;
    bf16*  xk_b     = (bf16*)(R_v + 8388608);

    // transposed-weight table
    bf16* W2T    = wbuf + 0;
    bf16* WqkvT  = wbuf + 65536;
    bf16* WoT    = wbuf + 262144;
    bf16* eff1T  = wbuf + 327680;
    bf16* eff2T  = wbuf + 589824;
    bf16* gatW0T = wbuf + 851968;
    bf16* gatW1T = wbuf + 917504;
    bf16* dgatW0T= wbuf + 983040;
    bf16* dgatW1T= wbuf + 1048576;
    bf16* clsWq0T= wbuf + 1114112;
    bf16* clsWk0T= wbuf + 1179648;
    bf16* clsWq1T= wbuf + 1245184;
    bf16* clsWk1T= wbuf + 1310720;
    PrepTab tab;
    tab.e[0]  = { W2,             0,       256,  256,  0    };
    tab.e[1]  = { Wqkv,           65536,   256,  768,  64   };
    tab.e[2]  = { Wo,             262144,  256,  256,  256  };
    tab.e[3]  = { eff1,           327680,  256,  1024, 320  };
    tab.e[4]  = { eff2,           589824,  1024, 256,  576  };
    tab.e[5]  = { gatW,           851968,  256,  256,  832  };
    tab.e[6]  = { gatW + 65536,   917504,  256,  256,  896  };
    tab.e[7]  = { dgatW,          983040,  256,  256,  960  };
    tab.e[8]  = { dgatW + 65536,  1048576, 256,  256,  1024 };
    tab.e[9]  = { clsWq,          1114112, 256,  256,  1088 };
    tab.e[10] = { clsWk,          1179648, 256,  256,  1152 };
    tab.e[11] = { clsWq + 65536,  1245184, 256,  256,  1216 };
    tab.e[12] = { clsWk + 65536,  1310720, 256,  256,  1280 };

    // prep + graph + embeddings
    k_prep<<<1344, 256, 0, stream>>>(tab, wbuf);
    k_nodes<<<64, 256, 0, stream>>>(tracks, dets, tmarks, dmarks, nodes);
    k_adjmask<<<16384, 256, 0, stream>>>(nodes, adjm_main, 1024, 10, 0);
    k_adjmask<<<8192, 256, 0, stream>>>(nodes, adjm_det, 512, 9, 512);
    k_featgemm<<<1152, 256, 0, stream>>>(tracks, dets, W1, b1, W2T, b2,
        emb_b, emb_r0_f, feat0_f, feat0_b, demb_b);

    // encoder (only r=0 row needed downstream of attention)
    k_ln_bf16<<<16384, 256, 0, stream>>>(emb_b, hln);
    k_gemm_bf16<<<dim3(8, 1024, 1), 256, 0, stream>>>(hln, 256, WqkvT + 65536, 256, kv_b, 512, 256, 0);
    k_gemm_bf16<<<dim3(4, 128, 1), 256, 0, stream>>>(hln, 2048, WqkvT, 256, q_b, 256, 256, 0);
    k_attn<<<8192, 256, 0, stream>>>(q_b, kv_b, o0_b);
    k_gemm_addres<<<dim3(4, 128, 1), 256, 0, stream>>>(o0_b, 256, WoT, 256, emb_r0_f, 256, x20, 256, 256);
    k_ln_f32<<<2048, 256, 0, stream>>>(x20, h2_b);
    k_gemm_bf16<<<dim3(16, 128, 1), 256, 0, stream>>>(h2_b, 256, eff1T, 256, f1_b, 1024, 256, 1);
    k_gemm_pred<<<dim3(4, 128, 1), 256, 0, stream>>>(f1_b, 1024, eff2T, 1024, emb_r0_f, x20, feat0_f, feat0_b, 1024);

    // main GAT layer 1
    k_gemm_T<<<dim3(256, 4, 1), 256, 0, stream>>>(gatW0T, feat0_b, hgT, 1024, 10);
    k_srcdst_T<<<256, 256, 0, stream>>>(hgT, gatA, (float*)src4, (float*)dst4, 1024, 10);
    k_maxdst<<<16, 256, 0, stream>>>(dst4, maxd4, 1024);
    k_gatagg_mm<<<512, 256, 0, stream>>>(hgT, adjm_main, src4, maxd4, dst4,
        feat0_f, 262144, xga_b, 1024);
    // main GAT layer 2
    k_gemm_T<<<dim3(256, 4, 1), 256, 0, stream>>>(gatW1T, xga_b, hgT, 1024, 10);
    k_srcdst_T<<<256, 256, 0, stream>>>(hgT, gatA + 512, (float*)src4, (float*)dst4, 1024, 10);
    k_maxdst<<<16, 256, 0, stream>>>(dst4, maxd4, 1024);
    k_gatagg_mm<<<512, 256, 0, stream>>>(hgT, adjm_main, src4, maxd4, dst4,
        feat0_f, 262144, xgb_b, 1024);
    // main scores + asso
    k_gemm_bf16<<<dim3(4, 256, 1), 256, 0, stream>>>(xgb_b, 256, clsWq0T, 256, xq_b, 256, 256, 0);
    k_gemm_bf16<<<dim3(4, 256, 1), 256, 0, stream>>>(xgb_b, 256, clsWk0T, 256, xk_b, 256, 256, 0);
    k_gemm_logits<<<dim3(16, 16, 16), 256, 0, stream>>>(xq_b, 262144L, xk_b, 262144L, 256,
        out, 1024, 1048576L, nodes, 0, out + 20971520L, 1);

    // det branch
    k_gemm_T<<<dim3(128, 4, 1), 256, 0, stream>>>(dgatW0T, demb_b, hgT, 512, 9);
    k_srcdst_T<<<128, 256, 0, stream>>>(hgT, dgatA, (float*)src4, (float*)dst4, 512, 9);
    k_maxdst<<<16, 256, 0, stream>>>(dst4, maxd4, 512);
    k_gatagg_mm<<<256, 256, 0, stream>>>(hgT, adjm_det, src4, maxd4, dst4,
        feat0_f + 131072, 262144, xga_b, 512);
    k_gemm_T<<<dim3(128, 4, 1), 256, 0, stream>>>(dgatW1T, xga_b, hgT, 512, 9);
    k_srcdst_T<<<128, 256, 0, stream>>>(hgT, dgatA + 512, (float*)src4, (float*)dst4, 512, 9);
    k_maxdst<<<16, 256, 0, stream>>>(dst4, maxd4, 512);
    k_gatagg_mm<<<256, 256, 0, stream>>>(hgT, adjm_det, src4, maxd4, dst4,
        feat0_f + 131072, 262144, xgb_b, 512);
    k_gemm_bf16<<<dim3(4, 128, 1), 256, 0, stream>>>(xgb_b, 256, clsWq1T, 256, xq_b, 256, 256, 0);
    k_gemm_bf16<<<dim3(4, 128, 1), 256, 0, stream>>>(xgb_b, 256, clsWk1T, 256, xk_b, 256, 256, 0);
    k_gemm_logits<<<dim3(8, 8, 16), 256, 0, stream>>>(xq_b, 131072L, xk_b, 131072L, 256,
        out + 16777216L, 512, 262144L, nodes, 512, (float*)nullptr, 2);
}

// Round 7
// 590.307 us; speedup vs baseline: 3.8677x; 1.0181x over previous
//
#include <hip/hip_runtime.h>
#include <math.h>

// ScatterNet_21706764714521 — round 7: 128x128 GEMM tiles (KV/eff1/logits),
// merged cls GEMMs, merged adjmask, maxdst fused into srcdst via atomicMax.
// fp32 I/O, bf16 MFMA inside.

typedef __bf16 bf16;
typedef __bf16 bf16x8 __attribute__((ext_vector_type(8)));
typedef __bf16 bf16x4 __attribute__((ext_vector_type(4)));
typedef float f32x4 __attribute__((ext_vector_type(4)));

__device__ __forceinline__ float bf2f(bf16 x) { return (float)x; }
__device__ __forceinline__ bf16 f2bf(float x) { return (bf16)x; }

// monotone float<->uint for atomicMax on signed floats
__device__ __forceinline__ unsigned encf(float f) {
    unsigned u = __float_as_uint(f);
    return (u & 0x80000000u) ? ~u : (u | 0x80000000u);
}
__device__ __forceinline__ float decf(unsigned u) {
    return (u & 0x80000000u) ? __uint_as_float(u & 0x7fffffffu)
                             : __uint_as_float(~u);
}

// node record: (x, y, invalid?1e9:0, 0). adjacency = dist<2 && both valid.
__device__ __forceinline__ bool node_adj(float4 a, float4 c) {
    float dx = a.x - c.x, dy = a.y - c.y;
    return (sqrtf(dx * dx + dy * dy) + a.z + c.z) < 2.0f;
}

// ---------------------------------------------------------------------------
// Weight prep: transpose+convert fp32 [R][C] -> bf16 [C][R], 32x32 tiles.
// ---------------------------------------------------------------------------
struct PrepEnt { const float* src; long dofs; int R; int C; int tstart; };
struct PrepTab { PrepEnt e[13]; };

__global__ __launch_bounds__(256) void k_prep(PrepTab tab, bf16* __restrict__ dst)
{
    __shared__ float tile[32][33];
    const int tid = blockIdx.x;
    int k = 0;
    #pragma unroll
    for (int q = 1; q < 13; ++q) if (tid >= tab.e[q].tstart) k = q;
    PrepEnt E = tab.e[k];
    const int local = tid - E.tstart;
    const int cT = E.C >> 5;
    const int tr = local / cT, tc = local - tr * cT;
    const int r0 = tr << 5, c0 = tc << 5;
    const int t = threadIdx.x;
    {
        int r = t >> 3, cq = (t & 7) * 4;
        *(float4*)&tile[r][cq] = *(const float4*)(E.src + (long)(r0 + r) * E.C + c0 + cq);
    }
    __syncthreads();
    {
        int c = t >> 3, rq = (t & 7) * 4;
        bf16x4 o;
        o[0] = f2bf(tile[rq + 0][c]); o[1] = f2bf(tile[rq + 1][c]);
        o[2] = f2bf(tile[rq + 2][c]); o[3] = f2bf(tile[rq + 3][c]);
        *(bf16x4*)(dst + E.dofs + (long)(c0 + c) * E.R + r0 + rq) = o;
    }
}

// ---------------------------------------------------------------------------
// 64x64 MFMA GEMM core (small/special GEMMs)
// D: row = m0 + wv*16 + kq*4 + i, col = n0 + nt*16 + lr.
// ---------------------------------------------------------------------------
__device__ __forceinline__ void gemm_bt(const bf16* __restrict__ A, int lda,
                                        const bf16* __restrict__ BT, int ldb,
                                        int K, f32x4 acc[4])
{
    __shared__ bf16 As[64][40];
    __shared__ bf16 Bs[64][40];
    const int t = threadIdx.x;
    const int m0 = blockIdx.y * 64;
    const int n0 = blockIdx.x * 64;
    const int lane = t & 63, wv = t >> 6, lr = lane & 15, kq = lane >> 4;
    const int arow = t >> 2, acol = (t & 3) * 8;
    for (int k0 = 0; k0 < K; k0 += 32) {
        __syncthreads();
        *(uint4*)&As[arow][acol] = *(const uint4*)(A + (long)(m0 + arow) * lda + k0 + acol);
        *(uint4*)&Bs[arow][acol] = *(const uint4*)(BT + (long)(n0 + arow) * ldb + k0 + acol);
        __syncthreads();
        bf16x8 af = *(const bf16x8*)&As[wv * 16 + lr][kq * 8];
        #pragma unroll
        for (int nt = 0; nt < 4; ++nt) {
            bf16x8 bfr = *(const bf16x8*)&Bs[nt * 16 + lr][kq * 8];
            acc[nt] = __builtin_amdgcn_mfma_f32_16x16x32_bf16(af, bfr, acc[nt], 0, 0, 0);
        }
    }
}

// ---------------------------------------------------------------------------
// 128x128 MFMA GEMM core. 4 waves; wave wv: rows [wv*32, wv*32+32), cols 0..127.
// D: row = m0 + wv*32 + mt*16 + kq*4 + i, col = n0 + nt*16 + lr.
// ---------------------------------------------------------------------------
__device__ __forceinline__ void gemm128_core(const bf16* __restrict__ A, int lda,
                                             const bf16* __restrict__ BT, int ldb,
                                             int m0, int n0, int K, f32x4 acc[2][8])
{
    __shared__ bf16 As[128][40];
    __shared__ bf16 Bs[128][40];
    const int t = threadIdx.x;
    const int lane = t & 63, wv = t >> 6, lr = lane & 15, kq = lane >> 4;
    const int srow = t >> 1, scol = (t & 1) * 16;
    for (int k0 = 0; k0 < K; k0 += 32) {
        __syncthreads();
        {
            const bf16* ap = A + (long)(m0 + srow) * lda + k0 + scol;
            *(uint4*)&As[srow][scol] = *(const uint4*)ap;
            *(uint4*)&As[srow][scol + 8] = *(const uint4*)(ap + 8);
            const bf16* bp = BT + (long)(n0 + srow) * ldb + k0 + scol;
            *(uint4*)&Bs[srow][scol] = *(const uint4*)bp;
            *(uint4*)&Bs[srow][scol + 8] = *(const uint4*)(bp + 8);
        }
        __syncthreads();
        bf16x8 af[2];
        af[0] = *(const bf16x8*)&As[wv * 32 + lr][kq * 8];
        af[1] = *(const bf16x8*)&As[wv * 32 + 16 + lr][kq * 8];
        #pragma unroll
        for (int nt = 0; nt < 8; ++nt) {
            bf16x8 bfr = *(const bf16x8*)&Bs[nt * 16 + lr][kq * 8];
            acc[0][nt] = __builtin_amdgcn_mfma_f32_16x16x32_bf16(af[0], bfr, acc[0][nt], 0, 0, 0);
            acc[1][nt] = __builtin_amdgcn_mfma_f32_16x16x32_bf16(af[1], bfr, acc[1][nt], 0, 0, 0);
        }
    }
}

__global__ __launch_bounds__(256) void k_gemm128_bf16(
    const bf16* __restrict__ A, int lda,
    const bf16* __restrict__ BT, int ldb,
    bf16* __restrict__ out, int ldo, int K, int relu)
{
    f32x4 acc[2][8] = {};
    const int m0 = blockIdx.y * 128, n0 = blockIdx.x * 128;
    gemm128_core(A, lda, BT, ldb, m0, n0, K, acc);
    const int lane = threadIdx.x & 63, wv = threadIdx.x >> 6;
    const int lr = lane & 15, kq = lane >> 4;
    #pragma unroll
    for (int mt = 0; mt < 2; ++mt) {
        #pragma unroll
        for (int nt = 0; nt < 8; ++nt) {
            int col = n0 + nt * 16 + lr;
            #pragma unroll
            for (int i = 0; i < 4; ++i) {
                int row = m0 + wv * 32 + mt * 16 + kq * 4 + i;
                float v = acc[mt][nt][i];
                if (relu) v = fmaxf(v, 0.f);
                out[(long)row * ldo + col] = f2bf(v);
            }
        }
    }
}

// scores = sigmoid(acc/16) * adj (adjacency from bitmask); asso copy / zero diag
__global__ __launch_bounds__(256) void k_gemm128_logits(
    const bf16* __restrict__ xqk, long sAz, int K,
    float* __restrict__ out, int ldo, long sOz,
    const unsigned long long* __restrict__ adjm, int nN, int nC,
    float* __restrict__ asso, int flags)
{
    f32x4 acc[2][8] = {};
    const int z = blockIdx.z;
    const int m0 = blockIdx.y * 128, n0 = blockIdx.x * 128;
    gemm128_core(xqk + z * sAz, 512, xqk + z * sAz + 256, 512, m0, n0, K, acc);
    const int lane = threadIdx.x & 63, wv = threadIdx.x >> 6;
    const int lr = lane & 15, kq = lane >> 4;
    float* ob = out + z * sOz;
    #pragma unroll
    for (int mt = 0; mt < 2; ++mt) {
        #pragma unroll
        for (int i = 0; i < 4; ++i) {
            int row = m0 + wv * 32 + mt * 16 + kq * 4 + i;
            unsigned long long w0 = adjm[((long)z * nN + row) * nC + (n0 >> 6)];
            unsigned long long w1 = adjm[((long)z * nN + row) * nC + (n0 >> 6) + 1];
            #pragma unroll
            for (int nt = 0; nt < 8; ++nt) {
                int col = n0 + nt * 16 + lr;
                int bp = nt * 16 + lr;
                bool adj = (bp < 64) ? ((w0 >> bp) & 1ull) : ((w1 >> (bp - 64)) & 1ull);
                if ((flags & 2) && row == col) adj = false;
                float v = 0.f;
                if (adj) v = 1.f / (1.f + __expf(-acc[mt][nt][i] * 0.0625f));
                ob[(long)row * ldo + col] = v;
                if ((flags & 1) && row < 512 && col >= 512)
                    asso[(long)z * 262144 + (long)row * 512 + (col - 512)] = v;
            }
        }
    }
}

__global__ __launch_bounds__(256) void k_gemm_bf16(
    const bf16* __restrict__ A, int lda,
    const bf16* __restrict__ BT, int ldb,
    bf16* __restrict__ out, int ldo, int K, int relu)
{
    f32x4 acc[4] = {};
    gemm_bt(A, lda, BT, ldb, K, acc);
    const int lane = threadIdx.x & 63, wv = threadIdx.x >> 6;
    const int lr = lane & 15, kq = lane >> 4;
    const int m0 = blockIdx.y * 64, n0 = blockIdx.x * 64;
    #pragma unroll
    for (int nt = 0; nt < 4; ++nt) {
        int col = n0 + nt * 16 + lr;
        #pragma unroll
        for (int i = 0; i < 4; ++i) {
            int row = m0 + wv * 16 + kq * 4 + i;
            float v = acc[nt][i];
            if (relu) v = fmaxf(v, 0.f);
            out[(long)row * ldo + col] = f2bf(v);
        }
    }
}

// out = res1 + acc (fp32 out)
__global__ __launch_bounds__(256) void k_gemm_addres(
    const bf16* __restrict__ A, int lda,
    const bf16* __restrict__ BT, int ldb,
    const float* __restrict__ res1, int ldr1,
    float* __restrict__ outf, int ldo, int K)
{
    f32x4 acc[4] = {};
    gemm_bt(A, lda, BT, ldb, K, acc);
    const int lane = threadIdx.x & 63, wv = threadIdx.x >> 6;
    const int lr = lane & 15, kq = lane >> 4;
    const int m0 = blockIdx.y * 64, n0 = blockIdx.x * 64;
    #pragma unroll
    for (int nt = 0; nt < 4; ++nt) {
        int col = n0 + nt * 16 + lr;
        #pragma unroll
        for (int i = 0; i < 4; ++i) {
            int row = m0 + wv * 16 + kq * 4 + i;
            outf[(long)row * ldo + col] = res1[(long)row * ldr1 + col] + acc[nt][i];
        }
    }
}

// predicted = tr_emb0 + 0.9*(x2_0 + ff2_out); scattered to feat0[b*1024+m]
__global__ __launch_bounds__(256) void k_gemm_pred(
    const bf16* __restrict__ A, int lda,
    const bf16* __restrict__ BT, int ldb,
    const float* __restrict__ res1, const float* __restrict__ res2,
    float* __restrict__ outf, bf16* __restrict__ outb, int K)
{
    f32x4 acc[4] = {};
    gemm_bt(A, lda, BT, ldb, K, acc);
    const int lane = threadIdx.x & 63, wv = threadIdx.x >> 6;
    const int lr = lane & 15, kq = lane >> 4;
    const int m0 = blockIdx.y * 64, n0 = blockIdx.x * 64;
    #pragma unroll
    for (int nt = 0; nt < 4; ++nt) {
        int col = n0 + nt * 16 + lr;
        #pragma unroll
        for (int i = 0; i < 4; ++i) {
            int row = m0 + wv * 16 + kq * 4 + i;     // b*512 + m
            float v = res1[(long)row * 256 + col]
                    + 0.9f * (res2[(long)row * 256 + col] + acc[nt][i]);
            long drow = (long)row + ((row >> 9) << 9);   // b*1024 + m
            long o = drow * 256 + col;
            outf[o] = v;
            outb[o] = f2bf(v);
        }
    }
}

// GAT projection, transposed output: hgT[b][d][j] = (X @ W)[b*nN+j][d]
__global__ __launch_bounds__(256) void k_gemm_T(
    const bf16* __restrict__ WT, const bf16* __restrict__ X,
    bf16* __restrict__ hgT, int nN, int nLog)
{
    f32x4 acc[4] = {};
    gemm_bt(WT, 256, X, 256, 256, acc);
    const int lane = threadIdx.x & 63, wv = threadIdx.x >> 6;
    const int lr = lane & 15, kq = lane >> 4;
    const int d0 = blockIdx.y * 64, n0 = blockIdx.x * 64;
    #pragma unroll
    for (int nt = 0; nt < 4; ++nt) {
        int node = n0 + nt * 16 + lr;
        int b = node >> nLog;
        int j = node & (nN - 1);
        #pragma unroll
        for (int i = 0; i < 4; ++i) {
            int d = d0 + wv * 16 + kq * 4 + i;
            hgT[((long)(b * 256 + d) << nLog) + j] = f2bf(acc[nt][i]);
        }
    }
}

// ---------------------------------------------------------------------------
// fused feat MLP, wide-N: block = 64 rows x all 256 cols.
// ---------------------------------------------------------------------------
__global__ __launch_bounds__(256) void k_featgemm(
    const float* __restrict__ tracks, const float* __restrict__ dets,
    const float* __restrict__ W1, const float* __restrict__ b1,
    const bf16* __restrict__ W2T, const float* __restrict__ b2,
    bf16* __restrict__ emb_b, float* __restrict__ emb_r0_f,
    float* __restrict__ feat0_f, bf16* __restrict__ feat0_b,
    bf16* __restrict__ demb_b)
{
    __shared__ float xr[64][4];
    __shared__ float w1s[4][256];
    __shared__ float b1s[256];
    __shared__ bf16 As[64][40];
    __shared__ bf16 Bs[256][40];
    const int t = threadIdx.x;
    const int m0 = blockIdx.x * 64;
    if (t < 64) {
        int gr = m0 + t;
        const float* sp = (gr < 65536) ? (tracks + (long)gr * 4)
                                       : (dets + (long)(gr - 65536) * 4);
        *(float4*)&xr[t][0] = *(const float4*)sp;
    }
    w1s[0][t] = W1[t];       w1s[1][t] = W1[256 + t];
    w1s[2][t] = W1[512 + t]; w1s[3][t] = W1[768 + t];
    b1s[t] = b1[t];
    const int arow = t >> 2, acol = (t & 3) * 8;
    const int lane = t & 63, wv = t >> 6, lr = lane & 15, kq = lane >> 4;
    f32x4 acc[16] = {};
    __syncthreads();
    for (int k0 = 0; k0 < 256; k0 += 32) {
        __syncthreads();
        #pragma unroll
        for (int j = 0; j < 8; ++j) {
            int c = k0 + acol + j;
            float v = fmaf(xr[arow][0], w1s[0][c],
                      fmaf(xr[arow][1], w1s[1][c],
                      fmaf(xr[arow][2], w1s[2][c],
                      fmaf(xr[arow][3], w1s[3][c], b1s[c]))));
            v = v > 0.f ? v : (__expf(v) - 1.f);
            As[arow][acol + j] = f2bf(v);
        }
        #pragma unroll
        for (int rr = 0; rr < 4; ++rr) {
            int n = rr * 64 + (t >> 2);
            *(uint4*)&Bs[n][acol] = *(const uint4*)(W2T + (long)n * 256 + k0 + acol);
        }
        __syncthreads();
        bf16x8 af = *(const bf16x8*)&As[wv * 16 + lr][kq * 8];
        #pragma unroll
        for (int nt = 0; nt < 16; ++nt) {
            bf16x8 bfr = *(const bf16x8*)&Bs[nt * 16 + lr][kq * 8];
            acc[nt] = __builtin_amdgcn_mfma_f32_16x16x32_bf16(af, bfr, acc[nt], 0, 0, 0);
        }
    }
    #pragma unroll
    for (int nt = 0; nt < 16; ++nt) {
        int col = nt * 16 + lr;
        float bv = b2[col];
        #pragma unroll
        for (int i = 0; i < 4; ++i) {
            int gr = m0 + wv * 16 + kq * 4 + i;
            float v = acc[nt][i] + bv;
            emb_b[(long)gr * 256 + col] = f2bf(v);
            if (gr < 65536) {
                if ((gr & 7) == 0) emb_r0_f[(long)(gr >> 3) * 256 + col] = v;
            } else {
                int dr = gr - 65536;
                long drow = ((long)(dr >> 9) << 10) + 512 + (dr & 511);
                feat0_f[drow * 256 + col] = v;
                feat0_b[drow * 256 + col] = f2bf(v);
                demb_b[(long)dr * 256 + col] = f2bf(v);
            }
        }
    }
}

// adjacency bitmask rows via ballot (main + det in one launch)
__global__ __launch_bounds__(256) void k_adjmask(
    const float4* __restrict__ nodes,
    unsigned long long* __restrict__ adjm_main,
    unsigned long long* __restrict__ adjm_det)
{
    int bi, nN, nLog, nodeOfs;
    unsigned long long* adjm;
    if (blockIdx.x < 16384) { bi = blockIdx.x; nN = 1024; nLog = 10; nodeOfs = 0; adjm = adjm_main; }
    else { bi = blockIdx.x - 16384; nN = 512; nLog = 9; nodeOfs = 512; adjm = adjm_det; }
    const int b = bi >> nLog;
    const int i = bi & (nN - 1);
    const float4* nb = nodes + b * 1024 + nodeOfs;
    const float4 ni = nb[i];
    const int t = threadIdx.x;
    const int w = t >> 6, lane = t & 63;
    const int nC = nN >> 6;
    for (int it = 0; it * 256 < nN; ++it) {
        int j = it * 256 + t;
        bool adj = node_adj(ni, nb[j]);
        unsigned long long mask = __ballot(adj);
        if (lane == 0) adjm[(long)bi * nC + it * 4 + w] = mask;
    }
}

// LayerNorm wave-per-row (4 rows/block)
__global__ __launch_bounds__(256) void k_ln_bf16(const bf16* __restrict__ x, bf16* __restrict__ out)
{
    const int w = threadIdx.x >> 6, l = threadIdx.x & 63;
    const long row = (long)blockIdx.x * 4 + w;
    bf16x4 xv = *(const bf16x4*)(x + row * 256 + l * 4);
    float v0 = bf2f(xv[0]), v1 = bf2f(xv[1]), v2 = bf2f(xv[2]), v3 = bf2f(xv[3]);
    float s = v0 + v1 + v2 + v3;
    #pragma unroll
    for (int o = 32; o; o >>= 1) s += __shfl_xor(s, o, 64);
    float mean = s * (1.f / 256.f);
    float d0 = v0 - mean, d1 = v1 - mean, d2 = v2 - mean, d3 = v3 - mean;
    float q = d0 * d0 + d1 * d1 + d2 * d2 + d3 * d3;
    #pragma unroll
    for (int o = 32; o; o >>= 1) q += __shfl_xor(q, o, 64);
    float rstd = rsqrtf(q * (1.f / 256.f) + 1e-5f);
    bf16x4 ov;
    ov[0] = f2bf(d0 * rstd); ov[1] = f2bf(d1 * rstd);
    ov[2] = f2bf(d2 * rstd); ov[3] = f2bf(d3 * rstd);
    *(bf16x4*)(out + row * 256 + l * 4) = ov;
}

__global__ __launch_bounds__(256) void k_ln_f32(const float* __restrict__ x, bf16* __restrict__ out)
{
    const int w = threadIdx.x >> 6, l = threadIdx.x & 63;
    const long row = (long)blockIdx.x * 4 + w;
    float4 xv = *(const float4*)(x + row * 256 + l * 4);
    float s = xv.x + xv.y + xv.z + xv.w;
    #pragma unroll
    for (int o = 32; o; o >>= 1) s += __shfl_xor(s, o, 64);
    float mean = s * (1.f / 256.f);
    float d0 = xv.x - mean, d1 = xv.y - mean, d2 = xv.z - mean, d3 = xv.w - mean;
    float q = d0 * d0 + d1 * d1 + d2 * d2 + d3 * d3;
    #pragma unroll
    for (int o = 32; o; o >>= 1) q += __shfl_xor(q, o, 64);
    float rstd = rsqrtf(q * (1.f / 256.f) + 1e-5f);
    bf16x4 ov;
    ov[0] = f2bf(d0 * rstd); ov[1] = f2bf(d1 * rstd);
    ov[2] = f2bf(d2 * rstd); ov[3] = f2bf(d3 * rstd);
    *(bf16x4*)(out + row * 256 + l * 4) = ov;
}

// encoder attention, r=0 row only. kv layout: [row][512]
__global__ __launch_bounds__(256) void k_attn(
    const bf16* __restrict__ q, const bf16* __restrict__ kv,
    bf16* __restrict__ o0)
{
    const long t = blockIdx.x;
    const int h = threadIdx.x >> 6;
    const int lane = threadIdx.x & 63;
    const int s = lane >> 3;
    const int dg = lane & 7;
    const bf16* qp = q + t * 256 + h * 64 + dg * 8;
    const bf16* kp = kv + (t * 8 + s) * 512 + h * 64 + dg * 8;
    float p = 0.f;
    #pragma unroll
    for (int e = 0; e < 8; ++e) p += bf2f(qp[e]) * bf2f(kp[e]);
    p += __shfl_xor(p, 1, 64);
    p += __shfl_xor(p, 2, 64);
    p += __shfl_xor(p, 4, 64);
    float sc = p * 0.125f;
    float w[8];
    float mx = -1e30f;
    #pragma unroll
    for (int s2 = 0; s2 < 8; ++s2) { w[s2] = __shfl(sc, s2 * 8, 64); mx = fmaxf(mx, w[s2]); }
    float sum = 0.f;
    #pragma unroll
    for (int s2 = 0; s2 < 8; ++s2) { w[s2] = __expf(w[s2] - mx); sum += w[s2]; }
    float rs = 1.f / sum;
    float acc = 0.f;
    const bf16* vp = kv + (t * 8) * 512 + 256 + h * 64 + lane;
    #pragma unroll
    for (int s2 = 0; s2 < 8; ++s2) acc += w[s2] * bf2f(vp[(long)s2 * 512]);
    o0[t * 256 + h * 64 + lane] = f2bf(acc * rs);
}

__global__ __launch_bounds__(256) void k_nodes(
    const float* __restrict__ tracks, const float* __restrict__ dets,
    const int* __restrict__ tm, const int* __restrict__ dm,
    float4* __restrict__ nodes, unsigned* __restrict__ maxd_all)
{
    int idx = blockIdx.x * 256 + threadIdx.x;
    if (blockIdx.x == 0) maxd_all[threadIdx.x] = 0x007fffffu;   // enc(-inf), 4 layers x 64
    int b = idx >> 10;
    int i = idx & 1023;
    float x, y;
    int valid;
    if (i < 512) {
        long o = (long)(b * 512 + i) * 32;
        x = tracks[o]; y = tracks[o + 1];
        valid = (i < tm[b]) ? 1 : 0;
    } else {
        int n = i - 512;
        long o = (long)(b * 512 + n) * 4;
        x = dets[o]; y = dets[o + 1];
        valid = (n < dm[b]) ? 1 : 0;
    }
    nodes[idx] = make_float4(x, y, valid ? 0.f : 1e9f, 0.f);
}

// GAT src/dst dots from hgT; block = 64 nodes x 4 heads; fused per-(b,h) dst max
__global__ __launch_bounds__(256) void k_srcdst_T(
    const bf16* __restrict__ hgT, const float* __restrict__ av,
    float* __restrict__ src, float* __restrict__ dst,
    unsigned* __restrict__ maxd_enc, int nN, int nLog)
{
    __shared__ float avs[512];
    const int t = threadIdx.x;
    avs[t] = av[t]; avs[256 + t] = av[256 + t];
    __syncthreads();
    const int jl = t & 63, h = t >> 6;
    const int n = blockIdx.x * 64 + jl;
    const int b = n >> nLog, j = n & (nN - 1);
    const bf16* base = hgT + (((long)b * 256 + h * 64) << nLog) + j;
    float p0 = 0.f, p1 = 0.f;
    #pragma unroll 8
    for (int dd = 0; dd < 64; ++dd) {
        float v = bf2f(base[(long)dd << nLog]);
        p0 += v * avs[h * 64 + dd];
        p1 += v * avs[256 + h * 64 + dd];
    }
    src[(long)n * 4 + h] = p0;
    dst[(long)n * 4 + h] = p1;
    float m = p1;
    #pragma unroll
    for (int o = 32; o; o >>= 1) m = fmaxf(m, __shfl_xor(m, o, 64));
    if (jl == 0) atomicMax(&maxd_enc[b * 4 + h], encf(m));
}

// GAT aggregation as MFMA GEMM with fused softmax denominator.
__global__ __launch_bounds__(256) void k_gatagg_mm(
    const bf16* __restrict__ hgT,
    const unsigned long long* __restrict__ adjm,
    const float4* __restrict__ srcv, const unsigned* __restrict__ maxd_enc,
    const float4* __restrict__ dstv,
    const float* __restrict__ res, int resBatchStride,
    bf16* __restrict__ outb, int nN)
{
    __shared__ float dstT[4][1024];
    __shared__ unsigned int adjW[32][33];
    const int t = threadIdx.x;
    const int nblk = nN >> 5;
    const int b = blockIdx.x / nblk;
    const int i0 = (blockIdx.x - b * nblk) << 5;
    const int nC = nN >> 6;
    for (int j = t; j < nN; j += 256) {
        float4 dj = dstv[(long)b * nN + j];
        dstT[0][j] = dj.x; dstT[1][j] = dj.y; dstT[2][j] = dj.z; dstT[3][j] = dj.w;
    }
    for (int idx = t; idx < 32 * nC; idx += 256) {
        int r = idx / nC, c = idx - r * nC;
        unsigned long long v = adjm[((long)b * nN + i0 + r) * nC + c];
        adjW[r][c * 2] = (unsigned)v;
        adjW[r][c * 2 + 1] = (unsigned)(v >> 32);
    }
    __syncthreads();
    const int h = t >> 6, lane = t & 63, lr = lane & 15, kq = lane >> 4;
    const float mdh = decf(maxd_enc[b * 4 + h]);
    float s_r[2], m_r[2], psum[2] = {0.f, 0.f};
    #pragma unroll
    for (int mt = 0; mt < 2; ++mt) {
        long idx = (long)b * nN + i0 + mt * 16 + lr;
        s_r[mt] = ((const float*)(srcv + idx))[h];
        float tmp = s_r[mt] + mdh;
        m_r[mt] = fmaxf(tmp, 0.2f * tmp);
    }
    f32x4 acc[2][4] = {};
    const bf16* hb = hgT + ((long)b * 256 + h * 64) * nN;
    for (int j0 = 0; j0 < nN; j0 += 32) {
        bf16x8 bfr[4];
        #pragma unroll
        for (int nt = 0; nt < 4; ++nt)
            bfr[nt] = *(const bf16x8*)(hb + (long)(nt * 16 + lr) * nN + j0 + kq * 8);
        #pragma unroll
        for (int mt = 0; mt < 2; ++mt) {
            unsigned byte = (adjW[mt * 16 + lr][j0 >> 5] >> (kq * 8)) & 0xffu;
            bf16x8 af;
            float ps = 0.f;
            #pragma unroll
            for (int jj = 0; jj < 8; ++jj) {
                float e = s_r[mt] + dstT[h][j0 + kq * 8 + jj];
                e = fmaxf(e, 0.2f * e);
                e = (byte & (1u << jj)) ? e : -1e9f;
                float p = __expf(e - m_r[mt]);
                af[jj] = f2bf(p);
                ps += p;
            }
            psum[mt] += ps;
            #pragma unroll
            for (int nt = 0; nt < 4; ++nt)
                acc[mt][nt] = __builtin_amdgcn_mfma_f32_16x16x32_bf16(af, bfr[nt], acc[mt][nt], 0, 0, 0);
        }
    }
    float stot[2];
    #pragma unroll
    for (int mt = 0; mt < 2; ++mt) {
        float v = psum[mt];
        v += __shfl_xor(v, 16, 64);
        v += __shfl_xor(v, 32, 64);
        stot[mt] = v;
    }
    #pragma unroll
    for (int mt = 0; mt < 2; ++mt) {
        #pragma unroll
        for (int ii = 0; ii < 4; ++ii) {
            int i = i0 + mt * 16 + kq * 4 + ii;
            long bi = (long)b * nN + i;
            float sv = __shfl(stot[mt], kq * 4 + ii, 64);
            float rs = 1.f / fmaxf(sv, 1e-30f);
            #pragma unroll
            for (int nt = 0; nt < 4; ++nt) {
                int col = h * 64 + nt * 16 + lr;
                float a = acc[mt][nt][ii] * rs;
                float e = a > 0.f ? a : expm1f(a);
                float v = 0.5f * e + 0.5f * res[(long)b * resBatchStride + (long)i * 256 + col];
                outb[bi * 256 + col] = f2bf(v);
            }
        }
    }
}

// ---------------------------------------------------------------------------
extern "C" void kernel_launch(void* const* d_in, const int* in_sizes, int n_in,
                              void* d_out, int out_size, void* d_ws, size_t ws_size,
                              hipStream_t stream)
{
    (void)in_sizes; (void)n_in; (void)out_size; (void)ws_size;
    const float* tracks = (const float*)d_in[0];
    const float* dets   = (const float*)d_in[1];
    const int*  tmarks = (const int*)d_in[2];
    const int*  dmarks = (const int*)d_in[3];
    const float* W1   = (const float*)d_in[4];
    const float* b1   = (const float*)d_in[5];
    const float* W2   = (const float*)d_in[6];
    const float* b2   = (const float*)d_in[7];
    const float* Wqkv = (const float*)d_in[8];
    const float* Wo   = (const float*)d_in[9];
    const float* eff1 = (const float*)d_in[10];
    const float* eff2 = (const float*)d_in[11];
    const float* gatW = (const float*)d_in[12];
    const float* gatA = (const float*)d_in[13];
    const float* dgatW = (const float*)d_in[14];
    const float* dgatA = (const float*)d_in[15];
    const float* clsWq = (const float*)d_in[16];
    const float* clsWk = (const float*)d_in[17];
    float* out = (float*)d_out;

    char* wsb = (char*)d_ws;
    size_t off = 0;
    auto take = [&](size_t bytes) -> char* {
        char* p = wsb + off;
        off += (bytes + 255) & ~(size_t)255;
        return p;
    };
    char* R_emb  = take(37748736);   // emb_b; later x20(+0), h2_b(+8388608)
    char* R_r0   = take(8388608);    // emb_r0_f
    char* R_hln  = take(33554432);   // hln; later f1_b
    char* R_v    = take(33554432);   // xqk buffers
    char* R_gat  = take(25165824);   // hgT(+0), xga_b(+8388608), xgb_b(+16777216)
    char* R_q    = take(4194304);    // q_b
    char* R_o0   = take(4194304);    // o0_b
    char* R_f0f  = take(16777216);   // feat0_f
    char* R_f0b  = take(8388608);    // feat0_b
    char* R_demb = take(4194304);    // demb_b
    float4* nodes = (float4*)take(262144);
    float4* src4  = (float4*)take(262144);
    float4* dst4  = (float4*)take(262144);
    unsigned* maxd_all = (unsigned*)take(1024);   // 4 layers x 16 b x 4 h
    unsigned long long* adjm_main = (unsigned long long*)take(2097152);
    unsigned long long* adjm_det  = (unsigned long long*)take(524288);
    bf16* wbuf = (bf16*)take(2752512);   // transposed bf16 weights

    bf16*  emb_b    = (bf16*)R_emb;
    float* emb_r0_f = (float*)R_r0;
    bf16*  hln      = (bf16*)R_hln;
    bf16*  kv_b     = (bf16*)d_out;         // 67MB scratch in d_out; dead before logits
    bf16*  q_b      = (bf16*)R_q;
    bf16*  o0_b     = (bf16*)R_o0;
    float* x20      = (float*)R_emb;
    bf16*  h2_b     = (bf16*)(R_emb + 8388608);
    bf16*  f1_b     = (bf16*)R_hln;
    float* feat0_f  = (float*)R_f0f;
    bf16*  feat0_b  = (bf16*)R_f0b;
    bf16*  demb_b   = (bf16*)R_demb;
    bf16*  hgT      = (bf16*)R_gat;
    bf16*  xga_b    = (bf16*)(R_gat + 8388608);
    bf16*  xgb_b    = (bf16*)(R_gat + 16777216);
    bf16*  xqk_b    = (bf16*)R_v;           // [row][512]: q cols 0..255, k 256..511

    // transposed-weight table
    bf16* W2T    = wbuf + 0;
    bf16* WqkvT  = wbuf + 65536;
    bf16* WoT    = wbuf + 262144;
    bf16* eff1T  = wbuf + 327680;
    bf16* eff2T  = wbuf + 589824;
    bf16* gatW0T = wbuf + 851968;
    bf16* gatW1T = wbuf + 917504;
    bf16* dgatW0T= wbuf + 983040;
    bf16* dgatW1T= wbuf + 1048576;
    bf16* clsQK0T= wbuf + 1114112;   // clsWq0T then clsWk0T (contiguous 512x256)
    bf16* clsQK1T= wbuf + 1245184;   // clsWq1T then clsWk1T
    PrepTab tab;
    tab.e[0]  = { W2,             0,       256,  256,  0    };
    tab.e[1]  = { Wqkv,           65536,   256,  768,  64   };
    tab.e[2]  = { Wo,             262144,  256,  256,  256  };
    tab.e[3]  = { eff1,           327680,  256,  1024, 320  };
    tab.e[4]  = { eff2,           589824,  1024, 256,  576  };
    tab.e[5]  = { gatW,           851968,  256,  256,  832  };
    tab.e[6]  = { gatW + 65536,   917504,  256,  256,  896  };
    tab.e[7]  = { dgatW,          983040,  256,  256,  960  };
    tab.e[8]  = { dgatW + 65536,  1048576, 256,  256,  1024 };
    tab.e[9]  = { clsWq,          1114112, 256,  256,  1088 };
    tab.e[10] = { clsWk,          1179648, 256,  256,  1152 };
    tab.e[11] = { clsWq + 65536,  1245184, 256,  256,  1216 };
    tab.e[12] = { clsWk + 65536,  1310720, 256,  256,  1280 };

    // prep + graph + embeddings
    k_prep<<<1344, 256, 0, stream>>>(tab, wbuf);
    k_nodes<<<64, 256, 0, stream>>>(tracks, dets, tmarks, dmarks, nodes, maxd_all);
    k_adjmask<<<24576, 256, 0, stream>>>(nodes, adjm_main, adjm_det);
    k_featgemm<<<1152, 256, 0, stream>>>(tracks, dets, W1, b1, W2T, b2,
        emb_b, emb_r0_f, feat0_f, feat0_b, demb_b);

    // encoder (only r=0 row needed downstream of attention)
    k_ln_bf16<<<16384, 256, 0, stream>>>(emb_b, hln);
    k_gemm128_bf16<<<dim3(4, 512, 1), 256, 0, stream>>>(hln, 256, WqkvT + 65536, 256, kv_b, 512, 256, 0);
    k_gemm_bf16<<<dim3(4, 128, 1), 256, 0, stream>>>(hln, 2048, WqkvT, 256, q_b, 256, 256, 0);
    k_attn<<<8192, 256, 0, stream>>>(q_b, kv_b, o0_b);
    k_gemm_addres<<<dim3(4, 128, 1), 256, 0, stream>>>(o0_b, 256, WoT, 256, emb_r0_f, 256, x20, 256, 256);
    k_ln_f32<<<2048, 256, 0, stream>>>(x20, h2_b);
    k_gemm128_bf16<<<dim3(8, 64, 1), 256, 0, stream>>>(h2_b, 256, eff1T, 256, f1_b, 1024, 256, 1);
    k_gemm_pred<<<dim3(4, 128, 1), 256, 0, stream>>>(f1_b, 1024, eff2T, 1024, emb_r0_f, x20, feat0_f, feat0_b, 1024);

    // main GAT layer 1
    k_gemm_T<<<dim3(256, 4, 1), 256, 0, stream>>>(gatW0T, feat0_b, hgT, 1024, 10);
    k_srcdst_T<<<256, 256, 0, stream>>>(hgT, gatA, (float*)src4, (float*)dst4, maxd_all, 1024, 10);
    k_gatagg_mm<<<512, 256, 0, stream>>>(hgT, adjm_main, src4, maxd_all, dst4,
        feat0_f, 262144, xga_b, 1024);
    // main GAT layer 2
    k_gemm_T<<<dim3(256, 4, 1), 256, 0, stream>>>(gatW1T, xga_b, hgT, 1024, 10);
    k_srcdst_T<<<256, 256, 0, stream>>>(hgT, gatA + 512, (float*)src4, (float*)dst4, maxd_all + 64, 1024, 10);
    k_gatagg_mm<<<512, 256, 0, stream>>>(hgT, adjm_main, src4, maxd_all + 64, dst4,
        feat0_f, 262144, xgb_b, 1024);
    // main scores + asso (merged q/k GEMM -> interleaved xqk, then 128-tile logits)
    k_gemm_bf16<<<dim3(8, 256, 1), 256, 0, stream>>>(xgb_b, 256, clsQK0T, 256, xqk_b, 512, 256, 0);
    k_gemm128_logits<<<dim3(8, 8, 16), 256, 0, stream>>>(xqk_b, 524288L, 256,
        out, 1024, 1048576L, adjm_main, 1024, 16, out + 20971520L, 1);

    // det branch
    k_gemm_T<<<dim3(128, 4, 1), 256, 0, stream>>>(dgatW0T, demb_b, hgT, 512, 9);
    k_srcdst_T<<<128, 256, 0, stream>>>(hgT, dgatA, (float*)src4, (float*)dst4, maxd_all + 128, 512, 9);
    k_gatagg_mm<<<256, 256, 0, stream>>>(hgT, adjm_det, src4, maxd_all + 128, dst4,
        feat0_f + 131072, 262144, xga_b, 512);
    k_gemm_T<<<dim3(128, 4, 1), 256, 0, stream>>>(dgatW1T, xga_b, hgT, 512, 9);
    k_srcdst_T<<<128, 256, 0, stream>>>(hgT, dgatA + 512, (float*)src4, (float*)dst4, maxd_all + 192, 512, 9);
    k_gatagg_mm<<<256, 256, 0, stream>>>(hgT, adjm_det, src4, maxd_all + 192, dst4,
        feat0_f + 131072, 262144, xgb_b, 512);
    k_gemm_bf16<<<dim3(8, 128, 1), 256, 0, stream>>>(xgb_b, 256, clsQK1T, 256, xqk_b, 512, 256, 0);
    k_gemm128_logits<<<dim3(4, 4, 16), 256, 0, stream>>>(xqk_b, 262144L, 256,
        out + 16777216L, 512, 262144L, adjm_det, 512, 8, (float*)nullptr, 2);
}